// Round 7
// baseline (194.375 us; speedup 1.0000x reference)
//
#include <hip/hip_runtime.h>
#include <hip/hip_bf16.h>

// Problem constants
#define B_ 2
#define S_ 2048
#define DM_ 1024
#define TD_ 1024
#define H_ 16
#define HD_ 64

using bf16 = __hip_bfloat16;
typedef __attribute__((ext_vector_type(8))) short s8v;   // 8 bf16 = one MFMA A/B frag
typedef __attribute__((ext_vector_type(4))) float f4v;   // MFMA C/D frag

__device__ __forceinline__ f4v mfma_bf16(s8v a, s8v b, f4v c) {
    return __builtin_amdgcn_mfma_f32_16x16x32_bf16(a, b, c, 0, 0, 0);
}

// HW packed fp32x2 -> bf16x2 (RNE), single VOP3 instr on CDNA3/4
__device__ __forceinline__ unsigned cvt_pk_bf16(float a, float b) {
    unsigned r;
    asm("v_cvt_pk_bf16_f32 %0, %1, %2" : "=v"(r) : "v"(a), "v"(b));
    return r;
}
__device__ __forceinline__ int2 pack4bf(float a, float b, float c, float d) {
    int2 r;
    r.x = (int)cvt_pk_bf16(a, b);
    r.y = (int)cvt_pk_bf16(c, d);
    return r;
}

// cos_q[0] == 1.0 exactly: fp32 word = 0x3F800000 (low16==0); bf16 pair != 0 low16.
__device__ __forceinline__ bool detect_f32(const unsigned int* __restrict__ cosw) {
    return (cosw[0] & 0xFFFFu) == 0u;
}

// async global -> LDS, 16 B per lane (HW: dst = wave-uniform base + lane*16)
__device__ __forceinline__ void gload_lds16(const bf16* g, void* l) {
    __builtin_amdgcn_global_load_lds(
        (const __attribute__((address_space(1))) unsigned int*)(const void*)g,
        (__attribute__((address_space(3))) unsigned int*)l,
        16, 0, 0);
}

#define NQ_  (B_ * S_ * DM_)
#define NWI_ (3 * TD_ * DM_)
#define NWO_ (DM_ * TD_)
#define NCVT_BLOCKS ((NQ_ + NWI_ + NWO_) / 2048)   // 4096

// ---------------------------------------------------------------------------
// Fused prep: blocks [0,4096) convert (query|W_in|W_out) -> bf16;
// blocks 4096..4097 compute lengths[b] from the mask (4-way storage detect).
// ---------------------------------------------------------------------------
__global__ __launch_bounds__(256)
void prep_all(const void* __restrict__ q, const void* __restrict__ wi,
              const void* __restrict__ wo, bf16* __restrict__ dst,
              const void* __restrict__ mask, int* __restrict__ lengths,
              const unsigned int* __restrict__ cosw) {
    const int bid = blockIdx.x;
    if (bid < NCVT_BLOCKS) {
        const bool f32 = detect_f32(cosw);
        int i = (bid * 256 + threadIdx.x) * 8;
        const void* src; int off;
        if (i < NQ_)              { src = q;  off = i; }
        else if (i < NQ_ + NWI_)  { src = wi; off = i - NQ_; }
        else                      { src = wo; off = i - NQ_ - NWI_; }
        if (f32) {
            const float* p = (const float*)src + off;
            float4 x = *reinterpret_cast<const float4*>(p);
            float4 y = *reinterpret_cast<const float4*>(p + 4);
            union { unsigned u[4]; int4 v; } t;
            t.u[0] = cvt_pk_bf16(x.x, x.y);
            t.u[1] = cvt_pk_bf16(x.z, x.w);
            t.u[2] = cvt_pk_bf16(y.x, y.y);
            t.u[3] = cvt_pk_bf16(y.z, y.w);
            *reinterpret_cast<int4*>(dst + i) = t.v;
        } else {
            *reinterpret_cast<int4*>(dst + i) =
                *reinterpret_cast<const int4*>((const bf16*)src + off);
        }
        return;
    }
    // lengths path
    int b = bid - NCVT_BLOCKS;
    unsigned int w0 = ((const unsigned int*)mask)[0];
    int enc;                 // 0=i32, 1=u8, 2=bf16, 3=f32
    if (w0 == 1u) enc = 0;
    else if (w0 == 0x01010101u) enc = 1;
    else if (w0 == 0x3F803F80u) enc = 2;
    else enc = 3;
    int cnt = 0;
    for (int s = threadIdx.x; s < S_; s += 256) {
        int i = b * S_ + s;
        bool v;
        if (enc == 0)      v = ((const int*)mask)[i] != 0;
        else if (enc == 1) v = ((const unsigned char*)mask)[i] != 0;
        else if (enc == 2) v = ((const unsigned short*)mask)[i] != 0;
        else               v = ((const float*)mask)[i] != 0.f;
        cnt += v ? 1 : 0;
    }
    __shared__ int red[256];
    red[threadIdx.x] = cnt;
    __syncthreads();
    for (int off = 128; off > 0; off >>= 1) {
        if (threadIdx.x < off) red[threadIdx.x] += red[threadIdx.x + off];
        __syncthreads();
    }
    if (threadIdx.x == 0) lengths[b] = red[0];
}

// ---------------------------------------------------------------------------
// Output-projection NT GEMM, BM=128 x BN=64, SINGLE-BARRIER DBUF PIPELINE:
// per K-step: issue STAGE(step+1 -> buf^1); ds_read+MFMA from buf; one
// __syncthreads() (its vmcnt(0) drain retires loads that flew during the
// MFMA phase). Buffer-swap safe: reads of buf^1 finished at the previous
// barrier (lgkmcnt(0) drained there). 48 KB LDS -> 3 blocks/CU.
// c_dyn: 1 -> write detected dtype (fp32 if inputs fp32), 0 -> bf16.
// ---------------------------------------------------------------------------
__global__ __launch_bounds__(256, 4)
void gemm_out(const bf16* __restrict__ A, const bf16* __restrict__ Bm,
              void* __restrict__ C, int M, int N, int K,
              int c_dyn, const unsigned int* __restrict__ cosw) {
    __shared__ bf16 lds_a[2][128 * 64];   // 32 KB dbuf, [row][chunk^(row&7)]
    __shared__ bf16 lds_b[2][64 * 64];    // 16 KB dbuf

    const bool cf32 = c_dyn && detect_f32(cosw);

    const int t = threadIdx.x;
    const int wave = t >> 6, lane = t & 63;
    const int quad = lane >> 4, l16 = lane & 15;
    const int wm = wave >> 1, wn = wave & 1;
    // bijective XCD-clustered decode: 512 blocks = 8 XCD x (4 m x 16 n)
    const int bid = blockIdx.x;
    const int c = bid & 7, g = bid >> 3;            // g: 0..63
    const int m0 = (c * 4 + (g & 3)) * 128;         // m_panel 0..31
    const int n0 = (g >> 2) * 64;                   // n_idx 0..15
    const int wuni = __builtin_amdgcn_readfirstlane(wave);

    f4v acc[4][2];
    #pragma unroll
    for (int i = 0; i < 4; i++)
        #pragma unroll
        for (int j = 0; j < 2; j++)
            acc[i][j] = f4v{0.f, 0.f, 0.f, 0.f};

    auto stage = [&](int k0, int buf) {
        #pragma unroll
        for (int i = 0; i < 4; i++) {
            int ci = i * 256 + t;        // A chunks 0..1023 (16B each)
            int row = ci >> 3;
            int csrc = (ci & 7) ^ (row & 7);
            gload_lds16(A + (size_t)(m0 + row) * K + k0 + csrc * 8,
                        (char*)lds_a[buf] + i * 4096 + wuni * 1024);
        }
        #pragma unroll
        for (int i = 0; i < 2; i++) {
            int ci = i * 256 + t;        // B chunks 0..511
            int row = ci >> 3;
            int csrc = (ci & 7) ^ (row & 7);
            gload_lds16(Bm + (size_t)(n0 + row) * K + k0 + csrc * 8,
                        (char*)lds_b[buf] + i * 4096 + wuni * 1024);
        }
    };

    const int nsteps = K >> 6;
    stage(0, 0);
    __syncthreads();                     // buf0 resident
    for (int step = 0; step < nsteps; step++) {
        const int cur = step & 1;
        if (step + 1 < nsteps) stage((step + 1) * 64, cur ^ 1);
        const bf16* la = lds_a[cur];
        const bf16* lb = lds_b[cur];
        #pragma unroll
        for (int kk = 0; kk < 2; kk++) {
            s8v afr[4], bfr[2];
            #pragma unroll
            for (int mb = 0; mb < 4; mb++) {
                int r = wm * 64 + mb * 16 + l16;
                int ch = (kk * 4 + quad) ^ (l16 & 7);
                afr[mb] = *reinterpret_cast<const s8v*>(&la[r * 64 + ch * 8]);
            }
            #pragma unroll
            for (int nb = 0; nb < 2; nb++) {
                int r = wn * 32 + nb * 16 + l16;
                int ch = (kk * 4 + quad) ^ (l16 & 7);
                bfr[nb] = *reinterpret_cast<const s8v*>(&lb[r * 64 + ch * 8]);
            }
            // swapped: D[i=n-in-16][j=m-in-16], lane j=l16, regs i=quad*4+rr
            #pragma unroll
            for (int mb = 0; mb < 4; mb++)
                #pragma unroll
                for (int nb = 0; nb < 2; nb++)
                    acc[mb][nb] = mfma_bf16(bfr[nb], afr[mb], acc[mb][nb]);
        }
        __syncthreads();                 // drains vmcnt+lgkm: next buf ready
    }

    // epilogue: m = m0+wm*64+mb*16+l16 (per lane), n = n0+wn*32+nb*16+quad*4+rr
    #pragma unroll
    for (int mb = 0; mb < 4; mb++) {
        int m = m0 + wm * 64 + mb * 16 + l16;
        #pragma unroll
        for (int nb = 0; nb < 2; nb++) {
            int n = n0 + wn * 32 + nb * 16 + quad * 4;
            f4v v = acc[mb][nb];
            if (cf32) {
                *reinterpret_cast<f4v*>(&((float*)C)[(size_t)m * N + n]) = v;
            } else {
                *reinterpret_cast<int2*>(&((bf16*)C)[(size_t)m * N + n]) =
                    pack4bf(v[0], v[1], v[2], v[3]);
            }
        }
    }
}

// ---------------------------------------------------------------------------
// QKV GEMM with FUSED RoPE + layout epilogue. BM=128 x BN=64, 4-way m-split
// per wave (wave = 32m x 64n, acc[2][4] = 32 AGPR + ~60 VGPR, lb(256,4)).
// SINGLE-BARRIER DBUF PIPELINE (round-6 post-mortem: the 2-barrier K-step
// had zero stage/MFMA overlap -> MfmaUtil 21%, 66% all-idle; this issues
// next-tile loads before the MFMA phase so the vmcnt(0) drain at the single
// barrier retires loads that flew under compute). 48 KB LDS -> 3 blocks/CU.
// m-split keeps wave n-span = 64 = ONE head -> RoPE partner (d+32)&63 stays
// at acc[mb][nb^2] on the same lane.
// Grid 1536 = 8 XCD x (4 m-panels x 48 n-panels), bijective XCD-clustered.
// Region by n0: [0,1024) Q, [1024,2048) K, [2048,3072) V.
// ---------------------------------------------------------------------------
__global__ __launch_bounds__(256, 4)
void gemm_qkv(const bf16* __restrict__ A, const bf16* __restrict__ Bm,
              bf16* __restrict__ Qh, bf16* __restrict__ Kt, bf16* __restrict__ Vt,
              const void* __restrict__ sin_t, const void* __restrict__ cos_t) {
    __shared__ bf16 lds_a[2][128 * 64];   // 32 KB dbuf, [row][chunk^(row&7)]
    __shared__ bf16 lds_b[2][64 * 64];    // 16 KB dbuf

    const int t = threadIdx.x;
    const int wave = t >> 6, lane = t & 63;
    const int quad = lane >> 4, l16 = lane & 15;
    // bijective XCD-clustered decode: 1536 blocks = 8 XCD x (4 m x 48 n)
    const int bid = blockIdx.x;
    const int c = bid & 7, g = bid >> 3;            // g: 0..191
    const int m0 = (c * 4 + (g & 3)) * 128;         // m_panel 0..31
    const int n0 = (g >> 2) * 64;                   // n_idx 0..47
    const int wuni = __builtin_amdgcn_readfirstlane(wave);

    f4v acc[2][4];
    #pragma unroll
    for (int i = 0; i < 2; i++)
        #pragma unroll
        for (int j = 0; j < 4; j++)
            acc[i][j] = f4v{0.f, 0.f, 0.f, 0.f};

    auto stage = [&](int k0, int buf) {
        #pragma unroll
        for (int i = 0; i < 4; i++) {
            int ci = i * 256 + t;        // A chunks 0..1023
            int row = ci >> 3;
            int csrc = (ci & 7) ^ (row & 7);
            gload_lds16(A + (size_t)(m0 + row) * 1024 + k0 + csrc * 8,
                        (char*)lds_a[buf] + i * 4096 + wuni * 1024);
        }
        #pragma unroll
        for (int i = 0; i < 2; i++) {
            int ci = i * 256 + t;        // B chunks 0..511
            int row = ci >> 3;
            int csrc = (ci & 7) ^ (row & 7);
            gload_lds16(Bm + (size_t)(n0 + row) * 1024 + k0 + csrc * 8,
                        (char*)lds_b[buf] + i * 4096 + wuni * 1024);
        }
    };

    stage(0, 0);
    __syncthreads();                     // buf0 resident
    for (int step = 0; step < 16; step++) {
        const int cur = step & 1;
        if (step < 15) stage((step + 1) * 64, cur ^ 1);
        const bf16* la = lds_a[cur];
        const bf16* lb = lds_b[cur];
        #pragma unroll
        for (int kk = 0; kk < 2; kk++) {
            s8v afr[2], bfr[4];
            #pragma unroll
            for (int mb = 0; mb < 2; mb++) {
                int r = wave * 32 + mb * 16 + l16;
                int ch = (kk * 4 + quad) ^ (l16 & 7);
                afr[mb] = *reinterpret_cast<const s8v*>(&la[r * 64 + ch * 8]);
            }
            #pragma unroll
            for (int nb = 0; nb < 4; nb++) {
                int r = nb * 16 + l16;
                int ch = (kk * 4 + quad) ^ (l16 & 7);
                bfr[nb] = *reinterpret_cast<const s8v*>(&lb[r * 64 + ch * 8]);
            }
            #pragma unroll
            for (int mb = 0; mb < 2; mb++)
                #pragma unroll
                for (int nb = 0; nb < 4; nb++)
                    acc[mb][nb] = mfma_bf16(bfr[nb], afr[mb], acc[mb][nb]);
        }
        __syncthreads();                 // drains vmcnt+lgkm: next buf ready
    }

    // ---- fused epilogue; n0 (block-uniform) selects region ----
    const int region = n0 >> 10;             // 0=Q, 1=K, 2=V
    if (region < 2) {
        const bool f32 = detect_f32((const unsigned int*)cos_t);
        #pragma unroll
        for (int mb = 0; mb < 2; mb++) {
            const int m = m0 + wave * 32 + mb * 16 + l16;
            const int b = m >> 11, s = m & 2047;
            #pragma unroll
            for (int nb = 0; nb < 4; nb++) {
                const int n = n0 + nb * 16 + quad * 4;
                const int d = n & 63;                 // = nb*16 + quad*4
                const int h = (n >> 6) & 15;
                const float sgn = (nb < 2) ? -1.f : 1.f;
                f4v v  = acc[mb][nb];
                f4v vp = acc[mb][nb ^ 2];             // partner (d+32)&63, same lane
                float cs[4], sn[4];
                if (f32) {
                    float4 c4 = *reinterpret_cast<const float4*>(
                        (const float*)cos_t + s * 64 + d);
                    float4 s4 = *reinterpret_cast<const float4*>(
                        (const float*)sin_t + s * 64 + d);
                    cs[0] = c4.x; cs[1] = c4.y; cs[2] = c4.z; cs[3] = c4.w;
                    sn[0] = s4.x; sn[1] = s4.y; sn[2] = s4.z; sn[3] = s4.w;
                } else {
                    const bf16* cp = (const bf16*)cos_t + s * 64 + d;
                    const bf16* sp = (const bf16*)sin_t + s * 64 + d;
                    #pragma unroll
                    for (int r = 0; r < 4; r++) {
                        cs[r] = __bfloat162float(cp[r]);
                        sn[r] = __bfloat162float(sp[r]);
                    }
                }
                float y[4];
                #pragma unroll
                for (int r = 0; r < 4; r++)
                    y[r] = v[r] * cs[r] + sgn * vp[r] * sn[r];
                if (region == 0) {
                    // Q: pre-scale 1/8 * log2(e) for exp2-based softmax
                    size_t o = ((size_t)(b * H_ + h) * S_ + s) * 64 + d;
                    *reinterpret_cast<int2*>(&Qh[o]) =
                        pack4bf(y[0] * 0.180336880f, y[1] * 0.180336880f,
                                y[2] * 0.180336880f, y[3] * 0.180336880f);
                } else {
                    size_t kt = ((size_t)(b * H_ + h) * 32 + (s >> 6)) * 4096;
                    int dp = ((((d >> 3) ^ (s & 7)) << 3) | (d & 7));
                    *reinterpret_cast<int2*>(&Kt[kt + (s & 63) * 64 + dp]) =
                        pack4bf(y[0], y[1], y[2], y[3]);
                }
            }
        }
    } else {
        // V: 128key x 64d tile of head h0 -> transpose via lds_a[0] (16 KB),
        // [key][dchunk^(key&7)] swizzle; then int4 stores to 2 Vt subtiles.
        // (final loop barrier guarantees all MFMA-phase reads complete)
        bf16* vtile = lds_a[0];
        #pragma unroll
        for (int mb = 0; mb < 2; mb++) {
            const int keyr = wave * 32 + mb * 16 + l16;   // 0..127
            #pragma unroll
            for (int nb = 0; nb < 4; nb++) {
                const int dl = nb * 16 + quad * 4;        // 0..63
                f4v v = acc[mb][nb];
                int off = (((dl >> 3) ^ (keyr & 7)) << 3) | (dl & 7);
                *reinterpret_cast<int2*>(&vtile[keyr * 64 + off]) =
                    pack4bf(v[0], v[1], v[2], v[3]);
            }
        }
        __syncthreads();
        const int b  = m0 >> 11;
        const int h0 = (n0 - 2048) >> 6;
        const int r0 = t & 7;                        // per-lane read rotation
        const short* lsrc = reinterpret_cast<const short*>(vtile);
        #pragma unroll
        for (int i = 0; i < 4; i++) {
            int id  = i * 256 + t;                   // 0..1023 int4 outputs
            int kc  = id & 7;                        // key 8-chunk in subtile
            int d   = (id >> 3) & 63;
            int sbl = id >> 9;                       // which 64-key subtile
            union { short s_[8]; int4 v4; } u;
            #pragma unroll
            for (int j = 0; j < 8; j++) {
                int e   = (j + r0) & 7;
                int key = sbl * 64 + kc * 8 + e;     // key&7 == e
                u.s_[e] = lsrc[key * 64 + (((d >> 3) ^ e) << 3) | (d & 7)];
            }
            size_t tb = ((size_t)(b * H_ + h0) * 32 +
                         ((m0 & 2047) >> 6) + sbl) * 4096;
            *reinterpret_cast<int4*>(&Vt[tb + d * 64 + ((kc ^ (d & 7)) << 3)]) = u.v4;
        }
    }
}

// ---------------------------------------------------------------------------
// Flash attention v6: transposed-S + depth-2 pipeline + CAUSAL PAIRING.
// 512 blocks; block handles qb = p (pass 0) and 31-p (pass 1): uniform 33
// tile-iters per block, exactly 2 blocks/CU, no scheduler churn/tail.
// XCD-clustered: bid&7 = XCD, all blocks of a (b,h) on one XCD (2 MB <= L2).
// Per iter: stage V[kt]+K[kt+1]; S-MFMA[kt]; exp/pack/PV[kt-1]; 1 barrier.
// s_setprio(1) wraps both MFMA clusters (T5: phase-diverse blocks/CU).
// ---------------------------------------------------------------------------
__global__ __launch_bounds__(256)
void attn_fused(const bf16* __restrict__ Qh, const bf16* __restrict__ Kt,
                const bf16* __restrict__ Vt, const int* __restrict__ lengths,
                bf16* __restrict__ out) {
    __shared__ bf16 k_buf[2 * 4096];   // K tiles  [row(key)][chunk^(key&7)]
    __shared__ bf16 v_buf[2 * 4096];   // Vt tiles [row(d)][keychunk^(d&7)]
    __shared__ bf16 lds_p[4 * 16 * 72];// per-wave P tile [qrow][key]

    const int t = threadIdx.x, wave = t >> 6, lane = t & 63;
    const int quad = lane >> 4, l16 = lane & 15;
    // XCD-clustered decode: 512 blocks, 64 slots/XCD = 4 bh x 16 pairs
    const int bid = blockIdx.x;
    const int slot = bid >> 3;                    // 0..63
    const int bh = (bid & 7) * 4 + (slot >> 4);   // all of a bh on one XCD
    const int p = slot & 15;                      // pair index
    const int b = bh >> 4, h = bh & 15;

    const size_t hb = (size_t)bh * S_ * 64;          // Qh base
    const bf16* Ktp = Kt + (size_t)bh * 32 * 4096;   // tile array base
    const bf16* Vtp = Vt + (size_t)bh * 32 * 4096;
    const int wuni = __builtin_amdgcn_readfirstlane(wave);
    int len_raw = lengths[b];
    const int len_b = len_raw < 1 ? 1 : (len_raw > S_ ? S_ : len_raw);
    const int nkt_len = (len_b + 63) >> 6;

    #pragma unroll
    for (int pass = 0; pass < 2; pass++) {
        const int qb = pass ? (31 - p) : p;
        const int qbase = qb * 64;
        const int qrow_g = qbase + wave * 16 + l16;   // this lane's q-row
        const int kmax = (qrow_g < len_b - 1) ? qrow_g : (len_b - 1);

        s8v qf[2];
        {
            const bf16* qptr = Qh + hb + (size_t)qrow_g * 64 + quad * 8;
            qf[0] = *reinterpret_cast<const s8v*>(qptr);
            qf[1] = *reinterpret_cast<const s8v*>(qptr + 32);
        }

        f4v o_acc[4];
        #pragma unroll
        for (int a = 0; a < 4; a++) o_acc[a] = f4v{0.f, 0.f, 0.f, 0.f};
        float l_sum = 0.f;

        const int nkt = (qb + 1) < nkt_len ? (qb + 1) : nkt_len;

        f4v s_prev[4];
        auto process_tile = [&](int pt, const bf16* vb) {
            const int pbase = pt * 64;
            const bool tail = (pt == qb) || (pbase + 64 > len_b);  // uniform
            #pragma unroll
            for (int a = 0; a < 4; a++) {
                float e0[4];
                #pragma unroll
                for (int r = 0; r < 4; r++) {
                    float e = __builtin_amdgcn_exp2f(s_prev[a][r]);
                    if (tail) {
                        int key = pbase + a * 16 + quad * 4 + r;
                        e = (key <= kmax) ? e : 0.f;
                    }
                    e0[r] = e;
                    l_sum += e;
                }
                *reinterpret_cast<int2*>(
                    &lds_p[(wave * 16 + l16) * 72 + a * 16 + quad * 4]) =
                    pack4bf(e0[0], e0[1], e0[2], e0[3]);
            }
            // wave-local: P writes -> P reads (lds_p region is per-wave)
            asm volatile("s_waitcnt lgkmcnt(0)" ::: "memory");
            __builtin_amdgcn_s_setprio(1);
            #pragma unroll
            for (int kk = 0; kk < 2; kk++) {
                s8v pf = *reinterpret_cast<const s8v*>(
                    &lds_p[(wave * 16 + l16) * 72 + kk * 32 + quad * 8]);
                #pragma unroll
                for (int a = 0; a < 4; a++) {
                    int ch = (kk * 4 + quad) ^ (l16 & 7);
                    s8v vf = *reinterpret_cast<const s8v*>(
                        &vb[(a * 16 + l16) * 64 + ch * 8]);
                    o_acc[a] = mfma_bf16(vf, pf, o_acc[a]);
                }
            }
            __builtin_amdgcn_s_setprio(0);
        };

        // prologue: stage K[0] (pass-0 drain reads only v_buf/lds_p; no race)
        #pragma unroll
        for (int i = 0; i < 2; i++) {
            int ci = i * 256 + t;
            gload_lds16(Ktp + ci * 8, (char*)k_buf + i * 4096 + wuni * 1024);
        }
        __syncthreads();   // K[0] resident (drains vmcnt)

        for (int kt = 0; kt < nkt; kt++) {
            const int cur = kt & 1;
            // stage V[kt] -> vbuf[cur] (one tile behind K)
            {
                const bf16* vst = Vtp + (size_t)kt * 4096;
                #pragma unroll
                for (int i = 0; i < 2; i++) {
                    int ci = i * 256 + t;
                    gload_lds16(vst + ci * 8,
                                (char*)v_buf + cur * 8192 + i * 4096 + wuni * 1024);
                }
            }
            // stage K[kt+1] -> kbuf[cur^1]
            if (kt + 1 < nkt) {
                const bf16* kst = Ktp + (size_t)(kt + 1) * 4096;
                #pragma unroll
                for (int i = 0; i < 2; i++) {
                    int ci = i * 256 + t;
                    gload_lds16(kst + ci * 8,
                                (char*)k_buf + (cur ^ 1) * 8192 + i * 4096 + wuni * 1024);
                }
            }

            // S^T[kt] = K Q^T : lane holds (key = a*16+quad*4+r, qrow = l16)
            const bf16* kb = k_buf + cur * 4096;
            f4v s_acc[4];
            #pragma unroll
            for (int a = 0; a < 4; a++) s_acc[a] = f4v{0.f, 0.f, 0.f, 0.f};
            __builtin_amdgcn_s_setprio(1);
            #pragma unroll
            for (int kk = 0; kk < 2; kk++) {
                #pragma unroll
                for (int a = 0; a < 4; a++) {
                    int ch = (kk * 4 + quad) ^ (l16 & 7);
                    s8v kf = *reinterpret_cast<const s8v*>(
                        &kb[(a * 16 + l16) * 64 + ch * 8]);
                    s_acc[a] = mfma_bf16(kf, qf[kk], s_acc[a]);
                }
            }
            __builtin_amdgcn_s_setprio(0);

            // overlap: previous tile's exp/pack/PV under this tile's S-MFMA
            if (kt > 0) process_tile(kt - 1, v_buf + ((kt - 1) & 1) * 4096);

            #pragma unroll
            for (int a = 0; a < 4; a++) s_prev[a] = s_acc[a];

            __syncthreads();   // V[kt], K[kt+1] staged; LDS reads done before reuse
        }
        // drain: last tile
        process_tile(nkt - 1, v_buf + ((nkt - 1) & 1) * 4096);

        // reduce l across the 4 quads sharing this q-row, then b64 epilogue
        l_sum += __shfl_xor(l_sum, 16);
        l_sum += __shfl_xor(l_sum, 32);
        float inv_l = 1.f / l_sum;
        size_t orow = ((size_t)(b * S_ + qrow_g)) * TD_ + h * 64;
        #pragma unroll
        for (int a = 0; a < 4; a++) {
            *reinterpret_cast<int2*>(&out[orow + a * 16 + quad * 4]) =
                pack4bf(o_acc[a][0] * inv_l, o_acc[a][1] * inv_l,
                        o_acc[a][2] * inv_l, o_acc[a][3] * inv_l);
        }
    }
}

// ---------------------------------------------------------------------------
extern "C" void kernel_launch(void* const* d_in, const int* in_sizes, int n_in,
                              void* d_out, int out_size, void* d_ws, size_t ws_size,
                              hipStream_t stream) {
    const void* query = d_in[0];   // [B,S,DM]  fp32 (auto-detected, bf16-safe)
    const void* W_in  = d_in[1];   // [3TD,DM]
    const void* W_out = d_in[2];   // [DM,TD]
    const void* sin_q = d_in[3];   // [S,HD]
    const void* cos_q = d_in[4];   // [S,HD]   dtype probe
    const void* mask  = d_in[5];   // [B,S] bool, storage auto-detected
    const unsigned int* cosw = (const unsigned int*)cos_q;

    const size_t nQ  = NQ_;   // 4194304
    const size_t nWi = NWI_;  // 3145728
    const size_t nWo = NWO_;  // 1048576

    // Workspace layout (no aliasing hazards: gemm_qkv reads qbf/wibf and
    // writes Qh/Kt/Vt; attn reads Qh/Kt/Vt and writes attn; all disjoint).
    bf16* base = (bf16*)d_ws;
    bf16* attn = base;                               // [4096,1024] attn out
    bf16* Vt   = base + (size_t)4096 * 1024;         // tiled+swizzled V
    bf16* Qh   = base + (size_t)2 * 4096 * 1024;     // [B,H,S,64] linear
    bf16* Kt   = Qh + nQ;                            // tiled+swizzled K
    bf16* qbf  = Kt + nQ;                            // query bf16
    bf16* wibf = qbf + nQ;
    bf16* wobf = wibf + nWi;
    int* lengths = (int*)(wobf + nWo);

    prep_all<<<NCVT_BLOCKS + B_, 256, 0, stream>>>(
        query, W_in, W_out, qbf, mask, lengths, cosw);

    gemm_qkv<<<1536, 256, 0, stream>>>(qbf, wibf, Qh, Kt, Vt, sin_q, cos_q);

    attn_fused<<<512, 256, 0, stream>>>(Qh, Kt, Vt, lengths, attn);

    gemm_out<<<512, 256, 0, stream>>>(attn, wobf, d_out, 4096, 1024, 1024, 1, cosw);
}

// Round 8
// 189.627 us; speedup vs baseline: 1.0250x; 1.0250x over previous
//
#include <hip/hip_runtime.h>
#include <hip/hip_bf16.h>

// Problem constants
#define B_ 2
#define S_ 2048
#define DM_ 1024
#define TD_ 1024
#define H_ 16
#define HD_ 64

using bf16 = __hip_bfloat16;
typedef __attribute__((ext_vector_type(8))) short s8v;   // 8 bf16 = one MFMA A/B frag
typedef __attribute__((ext_vector_type(4))) float f4v;   // MFMA C/D frag

__device__ __forceinline__ f4v mfma_bf16(s8v a, s8v b, f4v c) {
    return __builtin_amdgcn_mfma_f32_16x16x32_bf16(a, b, c, 0, 0, 0);
}

// HW packed fp32x2 -> bf16x2 (RNE), single VOP3 instr on CDNA3/4
__device__ __forceinline__ unsigned cvt_pk_bf16(float a, float b) {
    unsigned r;
    asm("v_cvt_pk_bf16_f32 %0, %1, %2" : "=v"(r) : "v"(a), "v"(b));
    return r;
}
__device__ __forceinline__ int2 pack4bf(float a, float b, float c, float d) {
    int2 r;
    r.x = (int)cvt_pk_bf16(a, b);
    r.y = (int)cvt_pk_bf16(c, d);
    return r;
}

// cos_q[0] == 1.0 exactly: fp32 word = 0x3F800000 (low16==0); bf16 pair != 0 low16.
__device__ __forceinline__ bool detect_f32(const unsigned int* __restrict__ cosw) {
    return (cosw[0] & 0xFFFFu) == 0u;
}

// async global -> LDS, 16 B per lane (HW: dst = wave-uniform base + lane*16)
__device__ __forceinline__ void gload_lds16(const bf16* g, void* l) {
    __builtin_amdgcn_global_load_lds(
        (const __attribute__((address_space(1))) unsigned int*)(const void*)g,
        (__attribute__((address_space(3))) unsigned int*)l,
        16, 0, 0);
}

#define NQ_  (B_ * S_ * DM_)
#define NWI_ (3 * TD_ * DM_)
#define NWO_ (DM_ * TD_)
#define NCVT_BLOCKS ((NQ_ + NWI_ + NWO_) / 2048)   // 4096

// ---------------------------------------------------------------------------
// Fused prep: blocks [0,4096) convert (query|W_in|W_out) -> bf16;
// blocks 4096..4097 compute lengths[b] from the mask (4-way storage detect).
// ---------------------------------------------------------------------------
__global__ __launch_bounds__(256)
void prep_all(const void* __restrict__ q, const void* __restrict__ wi,
              const void* __restrict__ wo, bf16* __restrict__ dst,
              const void* __restrict__ mask, int* __restrict__ lengths,
              const unsigned int* __restrict__ cosw) {
    const int bid = blockIdx.x;
    if (bid < NCVT_BLOCKS) {
        const bool f32 = detect_f32(cosw);
        int i = (bid * 256 + threadIdx.x) * 8;
        const void* src; int off;
        if (i < NQ_)              { src = q;  off = i; }
        else if (i < NQ_ + NWI_)  { src = wi; off = i - NQ_; }
        else                      { src = wo; off = i - NQ_ - NWI_; }
        if (f32) {
            const float* p = (const float*)src + off;
            float4 x = *reinterpret_cast<const float4*>(p);
            float4 y = *reinterpret_cast<const float4*>(p + 4);
            union { unsigned u[4]; int4 v; } t;
            t.u[0] = cvt_pk_bf16(x.x, x.y);
            t.u[1] = cvt_pk_bf16(x.z, x.w);
            t.u[2] = cvt_pk_bf16(y.x, y.y);
            t.u[3] = cvt_pk_bf16(y.z, y.w);
            *reinterpret_cast<int4*>(dst + i) = t.v;
        } else {
            *reinterpret_cast<int4*>(dst + i) =
                *reinterpret_cast<const int4*>((const bf16*)src + off);
        }
        return;
    }
    // lengths path
    int b = bid - NCVT_BLOCKS;
    unsigned int w0 = ((const unsigned int*)mask)[0];
    int enc;                 // 0=i32, 1=u8, 2=bf16, 3=f32
    if (w0 == 1u) enc = 0;
    else if (w0 == 0x01010101u) enc = 1;
    else if (w0 == 0x3F803F80u) enc = 2;
    else enc = 3;
    int cnt = 0;
    for (int s = threadIdx.x; s < S_; s += 256) {
        int i = b * S_ + s;
        bool v;
        if (enc == 0)      v = ((const int*)mask)[i] != 0;
        else if (enc == 1) v = ((const unsigned char*)mask)[i] != 0;
        else if (enc == 2) v = ((const unsigned short*)mask)[i] != 0;
        else               v = ((const float*)mask)[i] != 0.f;
        cnt += v ? 1 : 0;
    }
    __shared__ int red[256];
    red[threadIdx.x] = cnt;
    __syncthreads();
    for (int off = 128; off > 0; off >>= 1) {
        if (threadIdx.x < off) red[threadIdx.x] += red[threadIdx.x + off];
        __syncthreads();
    }
    if (threadIdx.x == 0) lengths[b] = red[0];
}

// ---------------------------------------------------------------------------
// Output-projection NT GEMM, BM=128 x BN=64 tile (512 blocks -> 2 blocks/CU,
// 2 waves/SIMD: one block's MFMA hides the other's staging). Proven R5 form;
// R7's dbuf variant regressed (bank contention + LDS occupancy loss).
// Wave covers 64m x 32n: acc[4][2] (32 AGPRs). XCD-clustered bid swizzle.
// c_dyn: 1 -> write detected dtype (fp32 if inputs fp32), 0 -> bf16.
// ---------------------------------------------------------------------------
__global__ __launch_bounds__(256, 4)
void gemm_out(const bf16* __restrict__ A, const bf16* __restrict__ Bm,
              void* __restrict__ C, int M, int N, int K,
              int c_dyn, const unsigned int* __restrict__ cosw) {
    __shared__ bf16 lds_a[128 * 64];   // 16 KB, [row][chunk^(row&7)]
    __shared__ bf16 lds_b[64 * 64];    //  8 KB

    const bool cf32 = c_dyn && detect_f32(cosw);

    const int t = threadIdx.x;
    const int wave = t >> 6, lane = t & 63;
    const int quad = lane >> 4, l16 = lane & 15;
    const int wm = wave >> 1, wn = wave & 1;
    // bijective XCD-clustered decode: 512 blocks = 8 XCD x (4 m x 16 n)
    const int bid = blockIdx.x;
    const int c = bid & 7, g = bid >> 3;            // g: 0..63
    const int m0 = (c * 4 + (g & 3)) * 128;         // m_panel 0..31
    const int n0 = (g >> 2) * 64;                   // n_idx 0..15
    const int wuni = __builtin_amdgcn_readfirstlane(wave);

    f4v acc[4][2];
    #pragma unroll
    for (int i = 0; i < 4; i++)
        #pragma unroll
        for (int j = 0; j < 2; j++)
            acc[i][j] = f4v{0.f, 0.f, 0.f, 0.f};

    for (int k0 = 0; k0 < K; k0 += 64) {
        __syncthreads();                 // prior reads done before restage
        #pragma unroll
        for (int i = 0; i < 4; i++) {
            int ci = i * 256 + t;        // A chunks 0..1023 (16B each)
            int row = ci >> 3;
            int csrc = (ci & 7) ^ (row & 7);
            gload_lds16(A + (size_t)(m0 + row) * K + k0 + csrc * 8,
                        (char*)lds_a + i * 4096 + wuni * 1024);
        }
        #pragma unroll
        for (int i = 0; i < 2; i++) {
            int ci = i * 256 + t;        // B chunks 0..511
            int row = ci >> 3;
            int csrc = (ci & 7) ^ (row & 7);
            gload_lds16(Bm + (size_t)(n0 + row) * K + k0 + csrc * 8,
                        (char*)lds_b + i * 4096 + wuni * 1024);
        }
        __syncthreads();                 // drains vmcnt -> staged data visible

        #pragma unroll
        for (int kk = 0; kk < 2; kk++) {
            s8v afr[4], bfr[2];
            #pragma unroll
            for (int mb = 0; mb < 4; mb++) {
                int r = wm * 64 + mb * 16 + l16;
                int ch = (kk * 4 + quad) ^ (l16 & 7);
                afr[mb] = *reinterpret_cast<const s8v*>(&lds_a[r * 64 + ch * 8]);
            }
            #pragma unroll
            for (int nb = 0; nb < 2; nb++) {
                int r = wn * 32 + nb * 16 + l16;
                int ch = (kk * 4 + quad) ^ (l16 & 7);
                bfr[nb] = *reinterpret_cast<const s8v*>(&lds_b[r * 64 + ch * 8]);
            }
            // swapped: D[i=n-in-16][j=m-in-16], lane j=l16, regs i=quad*4+rr
            #pragma unroll
            for (int mb = 0; mb < 4; mb++)
                #pragma unroll
                for (int nb = 0; nb < 2; nb++)
                    acc[mb][nb] = mfma_bf16(bfr[nb], afr[mb], acc[mb][nb]);
        }
    }

    // epilogue: m = m0+wm*64+mb*16+l16 (per lane), n = n0+wn*32+nb*16+quad*4+rr
    #pragma unroll
    for (int mb = 0; mb < 4; mb++) {
        int m = m0 + wm * 64 + mb * 16 + l16;
        #pragma unroll
        for (int nb = 0; nb < 2; nb++) {
            int n = n0 + wn * 32 + nb * 16 + quad * 4;
            f4v v = acc[mb][nb];
            if (cf32) {
                *reinterpret_cast<f4v*>(&((float*)C)[(size_t)m * N + n]) = v;
            } else {
                *reinterpret_cast<int2*>(&((bf16*)C)[(size_t)m * N + n]) =
                    pack4bf(v[0], v[1], v[2], v[3]);
            }
        }
    }
}

// ---------------------------------------------------------------------------
// QKV GEMM with FUSED RoPE + layout epilogue. PROVEN R5 FORM (44.2 us):
// 128x128 tile, 2-barrier K-step, lb(256,3) (3 waves/SIMD; the acc[4][4]=64
// AGPR + 72 VGPR = 136 regs/wave floor), XCD-clustered grid 768 (exactly
// 3 blocks/CU). R6 (m-split, more waves less work/wave) and R7 (dbuf,
// +LDS +bank-contention) both regressed -- this structure is the local opt.
// Region by n0: [0,1024) Q, [1024,2048) K, [2048,3072) V.
// ---------------------------------------------------------------------------
__global__ __launch_bounds__(256, 3)
void gemm_qkv(const bf16* __restrict__ A, const bf16* __restrict__ Bm,
              bf16* __restrict__ Qh, bf16* __restrict__ Kt, bf16* __restrict__ Vt,
              const void* __restrict__ sin_t, const void* __restrict__ cos_t) {
    __shared__ bf16 lds_a[128 * 64];   // 16 KB, [row][chunk^(row&7)]
    __shared__ bf16 lds_b[128 * 64];

    const int t = threadIdx.x;
    const int wave = t >> 6, lane = t & 63;
    const int quad = lane >> 4, l16 = lane & 15;
    const int wm = wave >> 1, wn = wave & 1;
    // bijective XCD-clustered decode: 768 blocks = 8 XCD x (4 m x 24 n)
    const int bid = blockIdx.x;
    const int c = bid & 7, g = bid >> 3;            // g: 0..95
    const int m0 = (c * 4 + (g & 3)) * 128;         // m_panel 0..31
    const int n0 = (g >> 2) * 128;                  // n_panel 0..23
    const int wuni = __builtin_amdgcn_readfirstlane(wave);

    f4v acc[4][4];
    #pragma unroll
    for (int i = 0; i < 4; i++)
        #pragma unroll
        for (int j = 0; j < 4; j++)
            acc[i][j] = f4v{0.f, 0.f, 0.f, 0.f};

    for (int k0 = 0; k0 < 1024; k0 += 64) {
        __syncthreads();
        #pragma unroll
        for (int i = 0; i < 4; i++) {
            int ci = i * 256 + t;
            int row = ci >> 3;
            int csrc = (ci & 7) ^ (row & 7);
            gload_lds16(A + (size_t)(m0 + row) * 1024 + k0 + csrc * 8,
                        (char*)lds_a + i * 4096 + wuni * 1024);
            gload_lds16(Bm + (size_t)(n0 + row) * 1024 + k0 + csrc * 8,
                        (char*)lds_b + i * 4096 + wuni * 1024);
        }
        __syncthreads();

        #pragma unroll
        for (int kk = 0; kk < 2; kk++) {
            s8v afr[4], bfr[4];
            #pragma unroll
            for (int mb = 0; mb < 4; mb++) {
                int r = wm * 64 + mb * 16 + l16;
                int ch = (kk * 4 + quad) ^ (l16 & 7);
                afr[mb] = *reinterpret_cast<const s8v*>(&lds_a[r * 64 + ch * 8]);
            }
            #pragma unroll
            for (int nb = 0; nb < 4; nb++) {
                int r = wn * 64 + nb * 16 + l16;
                int ch = (kk * 4 + quad) ^ (l16 & 7);
                bfr[nb] = *reinterpret_cast<const s8v*>(&lds_b[r * 64 + ch * 8]);
            }
            #pragma unroll
            for (int mb = 0; mb < 4; mb++)
                #pragma unroll
                for (int nb = 0; nb < 4; nb++)
                    acc[mb][nb] = mfma_bf16(bfr[nb], afr[mb], acc[mb][nb]);
        }
    }

    // ---- fused epilogue; n0 (wave-uniform) selects region ----
    const int region = n0 >> 10;             // 0=Q, 1=K, 2=V
    if (region < 2) {
        const bool f32 = detect_f32((const unsigned int*)cos_t);
        #pragma unroll
        for (int mb = 0; mb < 4; mb++) {
            const int m = m0 + wm * 64 + mb * 16 + l16;
            const int b = m >> 11, s = m & 2047;
            #pragma unroll
            for (int nb = 0; nb < 4; nb++) {
                const int n = n0 + wn * 64 + nb * 16 + quad * 4;
                const int d = n & 63;                 // = nb*16 + quad*4
                const int h = (n >> 6) & 15;
                const float sgn = (nb < 2) ? -1.f : 1.f;
                f4v v  = acc[mb][nb];
                f4v vp = acc[mb][nb ^ 2];             // partner (d+32)&63, same lane
                float cs[4], sn[4];
                if (f32) {
                    float4 c4 = *reinterpret_cast<const float4*>(
                        (const float*)cos_t + s * 64 + d);
                    float4 s4 = *reinterpret_cast<const float4*>(
                        (const float*)sin_t + s * 64 + d);
                    cs[0] = c4.x; cs[1] = c4.y; cs[2] = c4.z; cs[3] = c4.w;
                    sn[0] = s4.x; sn[1] = s4.y; sn[2] = s4.z; sn[3] = s4.w;
                } else {
                    const bf16* cp = (const bf16*)cos_t + s * 64 + d;
                    const bf16* sp = (const bf16*)sin_t + s * 64 + d;
                    #pragma unroll
                    for (int r = 0; r < 4; r++) {
                        cs[r] = __bfloat162float(cp[r]);
                        sn[r] = __bfloat162float(sp[r]);
                    }
                }
                float y[4];
                #pragma unroll
                for (int r = 0; r < 4; r++)
                    y[r] = v[r] * cs[r] + sgn * vp[r] * sn[r];
                if (region == 0) {
                    // Q: pre-scale 1/8 * log2(e) for exp2-based softmax
                    size_t o = ((size_t)(b * H_ + h) * S_ + s) * 64 + d;
                    *reinterpret_cast<int2*>(&Qh[o]) =
                        pack4bf(y[0] * 0.180336880f, y[1] * 0.180336880f,
                                y[2] * 0.180336880f, y[3] * 0.180336880f);
                } else {
                    size_t kt = ((size_t)(b * H_ + h) * 32 + (s >> 6)) * 4096;
                    int dp = ((((d >> 3) ^ (s & 7)) << 3) | (d & 7));
                    *reinterpret_cast<int2*>(&Kt[kt + (s & 63) * 64 + dp]) =
                        pack4bf(y[0], y[1], y[2], y[3]);
                }
            }
        }
    } else {
        // V: 128x128 LDS transpose. lds_a = rows 0..63, lds_b = rows 64..127
        // of the [key][d] tile (row stride 128, chunk-XOR swizzled by row&7).
        __syncthreads();                     // all MFMA-phase reads complete
        bf16* half_w = (wm == 0) ? lds_a : lds_b;   // wm picks row half
        #pragma unroll
        for (int mb = 0; mb < 4; mb++) {
            const int slr = mb * 16 + l16;           // row within half (0..63)
            #pragma unroll
            for (int nb = 0; nb < 4; nb++) {
                const int nl = wn * 64 + nb * 16 + quad * 4;  // local d 0..127
                f4v v = acc[mb][nb];
                // slr&7 == (wm*64+slr)&7: swizzle consistent across halves
                int off = (((nl >> 3) ^ (slr & 7)) << 3) | (nl & 7);
                *reinterpret_cast<int2*>(&half_w[slr * 128 + off]) =
                    pack4bf(v[0], v[1], v[2], v[3]);
            }
        }
        __syncthreads();
        const int b  = m0 >> 11;
        const int h0 = (n0 - 2048) >> 6;
        const int r0 = t & 7;                        // per-lane read rotation
        #pragma unroll
        for (int i = 0; i < 8; i++) {
            int id  = i * 256 + t;                   // 0..2047 int4 outputs
            int kc  = id & 7;                        // key 8-chunk
            int d   = (id >> 3) & 63;
            int sbl = (id >> 9) & 1;                 // which 64-key subtile
            int hh  = id >> 10;                      // which head half
            int cb  = (hh << 3) | (d >> 3);          // base LDS chunk of nl
            const short* half_r = reinterpret_cast<const short*>(
                sbl ? lds_b : lds_a);
            union { short s_[8]; int4 v4; } u;
            #pragma unroll
            for (int j = 0; j < 8; j++) {
                int e   = (j + r0) & 7;
                int slr = kc * 8 + e;                // row within half; slr&7==e
                u.s_[e] = half_r[slr * 128 + (((cb ^ e) << 3) | (d & 7))];
            }
            size_t tb = ((size_t)(b * H_ + h0 + hh) * 32 +
                         ((m0 & 2047) >> 6) + sbl) * 4096;
            *reinterpret_cast<int4*>(&Vt[tb + d * 64 + ((kc ^ (d & 7)) << 3)]) = u.v4;
        }
    }
}

// ---------------------------------------------------------------------------
// Flash attention v7: transposed-S + depth-2 pipeline, ONE qb PER BLOCK.
// 1024 blocks (vs 512 paired): LDS 41 KB -> 3 blocks/CU resident (was
// exactly 2 by grid), raising per-CU overlap of the stage->S-MFMA->exp->PV
// latency chain from 2-way to 3-way. qb assigned DESCENDING within each bh
// so long blocks (qb=31: 32 iters) dispatch first -> greedy makespan.
// XCD-clustered: bid&7 = XCD, 4 bh x 32 qb per XCD (K/V L2-resident).
// Per iter: stage V[kt]+K[kt+1]; S-MFMA[kt]; exp/pack/PV[kt-1]; 1 barrier.
// s_setprio(1) wraps both MFMA clusters (T5: phase-diverse blocks/CU).
// ---------------------------------------------------------------------------
__global__ __launch_bounds__(256)
void attn_fused(const bf16* __restrict__ Qh, const bf16* __restrict__ Kt,
                const bf16* __restrict__ Vt, const int* __restrict__ lengths,
                bf16* __restrict__ out) {
    __shared__ bf16 k_buf[2 * 4096];   // K tiles  [row(key)][chunk^(key&7)]
    __shared__ bf16 v_buf[2 * 4096];   // Vt tiles [row(d)][keychunk^(d&7)]
    __shared__ bf16 lds_p[4 * 16 * 72];// per-wave P tile [qrow][key]

    const int t = threadIdx.x, wave = t >> 6, lane = t & 63;
    const int quad = lane >> 4, l16 = lane & 15;
    // XCD-clustered decode: 1024 blocks, 128 slots/XCD = 4 bh x 32 qb
    const int bid = blockIdx.x;
    const int slot = bid >> 3;                    // 0..127
    const int bh = (bid & 7) * 4 + (slot >> 5);   // all of a bh on one XCD
    const int qb = 31 - (slot & 31);              // descending: big blocks first
    const int b = bh >> 4, h = bh & 15;

    const size_t hb = (size_t)bh * S_ * 64;          // Qh base
    const bf16* Ktp = Kt + (size_t)bh * 32 * 4096;   // tile array base
    const bf16* Vtp = Vt + (size_t)bh * 32 * 4096;
    const int wuni = __builtin_amdgcn_readfirstlane(wave);
    int len_raw = lengths[b];
    const int len_b = len_raw < 1 ? 1 : (len_raw > S_ ? S_ : len_raw);
    const int nkt_len = (len_b + 63) >> 6;

    const int qrow_g = qb * 64 + wave * 16 + l16;    // this lane's q-row
    const int kmax = (qrow_g < len_b - 1) ? qrow_g : (len_b - 1);

    s8v qf[2];
    {
        const bf16* qptr = Qh + hb + (size_t)qrow_g * 64 + quad * 8;
        qf[0] = *reinterpret_cast<const s8v*>(qptr);
        qf[1] = *reinterpret_cast<const s8v*>(qptr + 32);
    }

    f4v o_acc[4];
    #pragma unroll
    for (int a = 0; a < 4; a++) o_acc[a] = f4v{0.f, 0.f, 0.f, 0.f};
    float l_sum = 0.f;

    const int nkt = (qb + 1) < nkt_len ? (qb + 1) : nkt_len;

    f4v s_prev[4];
    auto process_tile = [&](int pt, const bf16* vb) {
        const int pbase = pt * 64;
        const bool tail = (pt == qb) || (pbase + 64 > len_b);  // uniform
        #pragma unroll
        for (int a = 0; a < 4; a++) {
            float e0[4];
            #pragma unroll
            for (int r = 0; r < 4; r++) {
                float e = __builtin_amdgcn_exp2f(s_prev[a][r]);
                if (tail) {
                    int key = pbase + a * 16 + quad * 4 + r;
                    e = (key <= kmax) ? e : 0.f;
                }
                e0[r] = e;
                l_sum += e;
            }
            *reinterpret_cast<int2*>(
                &lds_p[(wave * 16 + l16) * 72 + a * 16 + quad * 4]) =
                pack4bf(e0[0], e0[1], e0[2], e0[3]);
        }
        // wave-local: P writes -> P reads (lds_p region is per-wave)
        asm volatile("s_waitcnt lgkmcnt(0)" ::: "memory");
        __builtin_amdgcn_s_setprio(1);
        #pragma unroll
        for (int kk = 0; kk < 2; kk++) {
            s8v pf = *reinterpret_cast<const s8v*>(
                &lds_p[(wave * 16 + l16) * 72 + kk * 32 + quad * 8]);
            #pragma unroll
            for (int a = 0; a < 4; a++) {
                int ch = (kk * 4 + quad) ^ (l16 & 7);
                s8v vf = *reinterpret_cast<const s8v*>(
                    &vb[(a * 16 + l16) * 64 + ch * 8]);
                o_acc[a] = mfma_bf16(vf, pf, o_acc[a]);
            }
        }
        __builtin_amdgcn_s_setprio(0);
    };

    // prologue: stage K[0]
    #pragma unroll
    for (int i = 0; i < 2; i++) {
        int ci = i * 256 + t;
        gload_lds16(Ktp + ci * 8, (char*)k_buf + i * 4096 + wuni * 1024);
    }
    __syncthreads();   // K[0] resident (drains vmcnt)

    for (int kt = 0; kt < nkt; kt++) {
        const int cur = kt & 1;
        // stage V[kt] -> vbuf[cur] (one tile behind K)
        {
            const bf16* vst = Vtp + (size_t)kt * 4096;
            #pragma unroll
            for (int i = 0; i < 2; i++) {
                int ci = i * 256 + t;
                gload_lds16(vst + ci * 8,
                            (char*)v_buf + cur * 8192 + i * 4096 + wuni * 1024);
            }
        }
        // stage K[kt+1] -> kbuf[cur^1]
        if (kt + 1 < nkt) {
            const bf16* kst = Ktp + (size_t)(kt + 1) * 4096;
            #pragma unroll
            for (int i = 0; i < 2; i++) {
                int ci = i * 256 + t;
                gload_lds16(kst + ci * 8,
                            (char*)k_buf + (cur ^ 1) * 8192 + i * 4096 + wuni * 1024);
            }
        }

        // S^T[kt] = K Q^T : lane holds (key = a*16+quad*4+r, qrow = l16)
        const bf16* kb = k_buf + cur * 4096;
        f4v s_acc[4];
        #pragma unroll
        for (int a = 0; a < 4; a++) s_acc[a] = f4v{0.f, 0.f, 0.f, 0.f};
        __builtin_amdgcn_s_setprio(1);
        #pragma unroll
        for (int kk = 0; kk < 2; kk++) {
            #pragma unroll
            for (int a = 0; a < 4; a++) {
                int ch = (kk * 4 + quad) ^ (l16 & 7);
                s8v kf = *reinterpret_cast<const s8v*>(
                    &kb[(a * 16 + l16) * 64 + ch * 8]);
                s_acc[a] = mfma_bf16(kf, qf[kk], s_acc[a]);
            }
        }
        __builtin_amdgcn_s_setprio(0);

        // overlap: previous tile's exp/pack/PV under this tile's S-MFMA
        if (kt > 0) process_tile(kt - 1, v_buf + ((kt - 1) & 1) * 4096);

        #pragma unroll
        for (int a = 0; a < 4; a++) s_prev[a] = s_acc[a];

        __syncthreads();   // V[kt], K[kt+1] staged; LDS reads done before reuse
    }
    // drain: last tile
    process_tile(nkt - 1, v_buf + ((nkt - 1) & 1) * 4096);

    // reduce l across the 4 quads sharing this q-row, then b64 epilogue
    l_sum += __shfl_xor(l_sum, 16);
    l_sum += __shfl_xor(l_sum, 32);
    float inv_l = 1.f / l_sum;
    size_t orow = ((size_t)(b * S_ + qrow_g)) * TD_ + h * 64;
    #pragma unroll
    for (int a = 0; a < 4; a++) {
        *reinterpret_cast<int2*>(&out[orow + a * 16 + quad * 4]) =
            pack4bf(o_acc[a][0] * inv_l, o_acc[a][1] * inv_l,
                    o_acc[a][2] * inv_l, o_acc[a][3] * inv_l);
    }
}

// ---------------------------------------------------------------------------
extern "C" void kernel_launch(void* const* d_in, const int* in_sizes, int n_in,
                              void* d_out, int out_size, void* d_ws, size_t ws_size,
                              hipStream_t stream) {
    const void* query = d_in[0];   // [B,S,DM]  fp32 (auto-detected, bf16-safe)
    const void* W_in  = d_in[1];   // [3TD,DM]
    const void* W_out = d_in[2];   // [DM,TD]
    const void* sin_q = d_in[3];   // [S,HD]
    const void* cos_q = d_in[4];   // [S,HD]   dtype probe
    const void* mask  = d_in[5];   // [B,S] bool, storage auto-detected
    const unsigned int* cosw = (const unsigned int*)cos_q;

    const size_t nQ  = NQ_;   // 4194304
    const size_t nWi = NWI_;  // 3145728
    const size_t nWo = NWO_;  // 1048576

    // Workspace layout (no aliasing hazards: gemm_qkv reads qbf/wibf and
    // writes Qh/Kt/Vt; attn reads Qh/Kt/Vt and writes attn; all disjoint).
    bf16* base = (bf16*)d_ws;
    bf16* attn = base;                               // [4096,1024] attn out
    bf16* Vt   = base + (size_t)4096 * 1024;         // tiled+swizzled V
    bf16* Qh   = base + (size_t)2 * 4096 * 1024;     // [B,H,S,64] linear
    bf16* Kt   = Qh + nQ;                            // tiled+swizzled K
    bf16* qbf  = Kt + nQ;                            // query bf16
    bf16* wibf = qbf + nQ;
    bf16* wobf = wibf + nWi;
    int* lengths = (int*)(wobf + nWo);

    prep_all<<<NCVT_BLOCKS + B_, 256, 0, stream>>>(
        query, W_in, W_out, qbf, mask, lengths, cosw);

    gemm_qkv<<<768, 256, 0, stream>>>(qbf, wibf, Qh, Kt, Vt, sin_q, cos_q);

    attn_fused<<<1024, 256, 0, stream>>>(Qh, Kt, Vt, lengths, attn);

    gemm_out<<<512, 256, 0, stream>>>(attn, wobf, d_out, 4096, 1024, 1024, 1, cosw);
}

// Round 9
// 179.872 us; speedup vs baseline: 1.0806x; 1.0542x over previous
//
#include <hip/hip_runtime.h>
#include <hip/hip_bf16.h>

// Problem constants
#define B_ 2
#define S_ 2048
#define DM_ 1024
#define TD_ 1024
#define H_ 16
#define HD_ 64

using bf16 = __hip_bfloat16;
typedef __attribute__((ext_vector_type(8))) short s8v;   // 8 bf16 = one MFMA A/B frag
typedef __attribute__((ext_vector_type(4))) float f4v;   // MFMA C/D frag

__device__ __forceinline__ f4v mfma_bf16(s8v a, s8v b, f4v c) {
    return __builtin_amdgcn_mfma_f32_16x16x32_bf16(a, b, c, 0, 0, 0);
}

// HW packed fp32x2 -> bf16x2 (RNE), single VOP3 instr on CDNA3/4
__device__ __forceinline__ unsigned cvt_pk_bf16(float a, float b) {
    unsigned r;
    asm("v_cvt_pk_bf16_f32 %0, %1, %2" : "=v"(r) : "v"(a), "v"(b));
    return r;
}
__device__ __forceinline__ int2 pack4bf(float a, float b, float c, float d) {
    int2 r;
    r.x = (int)cvt_pk_bf16(a, b);
    r.y = (int)cvt_pk_bf16(c, d);
    return r;
}

// cos_q[0] == 1.0 exactly: fp32 word = 0x3F800000 (low16==0); bf16 pair != 0 low16.
__device__ __forceinline__ bool detect_f32(const unsigned int* __restrict__ cosw) {
    return (cosw[0] & 0xFFFFu) == 0u;
}

// async global -> LDS, 16 B per lane (HW: dst = wave-uniform base + lane*16)
__device__ __forceinline__ void gload_lds16(const bf16* g, void* l) {
    __builtin_amdgcn_global_load_lds(
        (const __attribute__((address_space(1))) unsigned int*)(const void*)g,
        (__attribute__((address_space(3))) unsigned int*)l,
        16, 0, 0);
}

#define NQ_  (B_ * S_ * DM_)
#define NWI_ (3 * TD_ * DM_)
#define NWO_ (DM_ * TD_)
#define NCVT_BLOCKS ((NQ_ + NWI_ + NWO_) / 2048)   // 4096

// ---------------------------------------------------------------------------
// Fused prep: blocks [0,4096) convert (query|W_in|W_out) -> bf16;
// blocks 4096..4097 compute lengths[b] from the mask (4-way storage detect).
// ---------------------------------------------------------------------------
__global__ __launch_bounds__(256)
void prep_all(const void* __restrict__ q, const void* __restrict__ wi,
              const void* __restrict__ wo, bf16* __restrict__ dst,
              const void* __restrict__ mask, int* __restrict__ lengths,
              const unsigned int* __restrict__ cosw) {
    const int bid = blockIdx.x;
    if (bid < NCVT_BLOCKS) {
        const bool f32 = detect_f32(cosw);
        int i = (bid * 256 + threadIdx.x) * 8;
        const void* src; int off;
        if (i < NQ_)              { src = q;  off = i; }
        else if (i < NQ_ + NWI_)  { src = wi; off = i - NQ_; }
        else                      { src = wo; off = i - NQ_ - NWI_; }
        if (f32) {
            const float* p = (const float*)src + off;
            float4 x = *reinterpret_cast<const float4*>(p);
            float4 y = *reinterpret_cast<const float4*>(p + 4);
            union { unsigned u[4]; int4 v; } t;
            t.u[0] = cvt_pk_bf16(x.x, x.y);
            t.u[1] = cvt_pk_bf16(x.z, x.w);
            t.u[2] = cvt_pk_bf16(y.x, y.y);
            t.u[3] = cvt_pk_bf16(y.z, y.w);
            *reinterpret_cast<int4*>(dst + i) = t.v;
        } else {
            *reinterpret_cast<int4*>(dst + i) =
                *reinterpret_cast<const int4*>((const bf16*)src + off);
        }
        return;
    }
    // lengths path
    int b = bid - NCVT_BLOCKS;
    unsigned int w0 = ((const unsigned int*)mask)[0];
    int enc;                 // 0=i32, 1=u8, 2=bf16, 3=f32
    if (w0 == 1u) enc = 0;
    else if (w0 == 0x01010101u) enc = 1;
    else if (w0 == 0x3F803F80u) enc = 2;
    else enc = 3;
    int cnt = 0;
    for (int s = threadIdx.x; s < S_; s += 256) {
        int i = b * S_ + s;
        bool v;
        if (enc == 0)      v = ((const int*)mask)[i] != 0;
        else if (enc == 1) v = ((const unsigned char*)mask)[i] != 0;
        else if (enc == 2) v = ((const unsigned short*)mask)[i] != 0;
        else               v = ((const float*)mask)[i] != 0.f;
        cnt += v ? 1 : 0;
    }
    __shared__ int red[256];
    red[threadIdx.x] = cnt;
    __syncthreads();
    for (int off = 128; off > 0; off >>= 1) {
        if (threadIdx.x < off) red[threadIdx.x] += red[threadIdx.x + off];
        __syncthreads();
    }
    if (threadIdx.x == 0) lengths[b] = red[0];
}

// ---------------------------------------------------------------------------
// Output-projection NT GEMM, BM=128 x BN=64 tile (512 blocks -> 2 blocks/CU,
// 2 waves/SIMD: one block's MFMA hides the other's staging). Proven R5 form.
// Wave covers 64m x 32n: acc[4][2] (32 AGPRs). XCD-clustered bid swizzle.
// c_dyn: 1 -> write detected dtype (fp32 if inputs fp32), 0 -> bf16.
// ---------------------------------------------------------------------------
__global__ __launch_bounds__(256, 4)
void gemm_out(const bf16* __restrict__ A, const bf16* __restrict__ Bm,
              void* __restrict__ C, int M, int N, int K,
              int c_dyn, const unsigned int* __restrict__ cosw) {
    __shared__ bf16 lds_a[128 * 64];   // 16 KB, [row][chunk^(row&7)]
    __shared__ bf16 lds_b[64 * 64];    //  8 KB

    const bool cf32 = c_dyn && detect_f32(cosw);

    const int t = threadIdx.x;
    const int wave = t >> 6, lane = t & 63;
    const int quad = lane >> 4, l16 = lane & 15;
    const int wm = wave >> 1, wn = wave & 1;
    // bijective XCD-clustered decode: 512 blocks = 8 XCD x (4 m x 16 n)
    const int bid = blockIdx.x;
    const int c = bid & 7, g = bid >> 3;            // g: 0..63
    const int m0 = (c * 4 + (g & 3)) * 128;         // m_panel 0..31
    const int n0 = (g >> 2) * 64;                   // n_idx 0..15
    const int wuni = __builtin_amdgcn_readfirstlane(wave);

    f4v acc[4][2];
    #pragma unroll
    for (int i = 0; i < 4; i++)
        #pragma unroll
        for (int j = 0; j < 2; j++)
            acc[i][j] = f4v{0.f, 0.f, 0.f, 0.f};

    for (int k0 = 0; k0 < K; k0 += 64) {
        __syncthreads();                 // prior reads done before restage
        #pragma unroll
        for (int i = 0; i < 4; i++) {
            int ci = i * 256 + t;        // A chunks 0..1023 (16B each)
            int row = ci >> 3;
            int csrc = (ci & 7) ^ (row & 7);
            gload_lds16(A + (size_t)(m0 + row) * K + k0 + csrc * 8,
                        (char*)lds_a + i * 4096 + wuni * 1024);
        }
        #pragma unroll
        for (int i = 0; i < 2; i++) {
            int ci = i * 256 + t;        // B chunks 0..511
            int row = ci >> 3;
            int csrc = (ci & 7) ^ (row & 7);
            gload_lds16(Bm + (size_t)(n0 + row) * K + k0 + csrc * 8,
                        (char*)lds_b + i * 4096 + wuni * 1024);
        }
        __syncthreads();                 // drains vmcnt -> staged data visible

        #pragma unroll
        for (int kk = 0; kk < 2; kk++) {
            s8v afr[4], bfr[2];
            #pragma unroll
            for (int mb = 0; mb < 4; mb++) {
                int r = wm * 64 + mb * 16 + l16;
                int ch = (kk * 4 + quad) ^ (l16 & 7);
                afr[mb] = *reinterpret_cast<const s8v*>(&lds_a[r * 64 + ch * 8]);
            }
            #pragma unroll
            for (int nb = 0; nb < 2; nb++) {
                int r = wn * 32 + nb * 16 + l16;
                int ch = (kk * 4 + quad) ^ (l16 & 7);
                bfr[nb] = *reinterpret_cast<const s8v*>(&lds_b[r * 64 + ch * 8]);
            }
            // swapped: D[i=n-in-16][j=m-in-16], lane j=l16, regs i=quad*4+rr
            #pragma unroll
            for (int mb = 0; mb < 4; mb++)
                #pragma unroll
                for (int nb = 0; nb < 2; nb++)
                    acc[mb][nb] = mfma_bf16(bfr[nb], afr[mb], acc[mb][nb]);
        }
    }

    // epilogue: m = m0+wm*64+mb*16+l16 (per lane), n = n0+wn*32+nb*16+quad*4+rr
    #pragma unroll
    for (int mb = 0; mb < 4; mb++) {
        int m = m0 + wm * 64 + mb * 16 + l16;
        #pragma unroll
        for (int nb = 0; nb < 2; nb++) {
            int n = n0 + wn * 32 + nb * 16 + quad * 4;
            f4v v = acc[mb][nb];
            if (cf32) {
                *reinterpret_cast<f4v*>(&((float*)C)[(size_t)m * N + n]) = v;
            } else {
                *reinterpret_cast<int2*>(&((bf16*)C)[(size_t)m * N + n]) =
                    pack4bf(v[0], v[1], v[2], v[3]);
            }
        }
    }
}

// ---------------------------------------------------------------------------
// QKV GEMM with FUSED RoPE + layout epilogue. PROVEN R5 FORM (44.2 us):
// 128x128 tile, 2-barrier K-step, lb(256,3), XCD-clustered grid 768.
// R6 (m-split) and R7 (dbuf) both regressed -- this is the local opt.
// Region by n0: [0,1024) Q, [1024,2048) K, [2048,3072) V.
// ---------------------------------------------------------------------------
__global__ __launch_bounds__(256, 3)
void gemm_qkv(const bf16* __restrict__ A, const bf16* __restrict__ Bm,
              bf16* __restrict__ Qh, bf16* __restrict__ Kt, bf16* __restrict__ Vt,
              const void* __restrict__ sin_t, const void* __restrict__ cos_t) {
    __shared__ bf16 lds_a[128 * 64];   // 16 KB, [row][chunk^(row&7)]
    __shared__ bf16 lds_b[128 * 64];

    const int t = threadIdx.x;
    const int wave = t >> 6, lane = t & 63;
    const int quad = lane >> 4, l16 = lane & 15;
    const int wm = wave >> 1, wn = wave & 1;
    // bijective XCD-clustered decode: 768 blocks = 8 XCD x (4 m x 24 n)
    const int bid = blockIdx.x;
    const int c = bid & 7, g = bid >> 3;            // g: 0..95
    const int m0 = (c * 4 + (g & 3)) * 128;         // m_panel 0..31
    const int n0 = (g >> 2) * 128;                  // n_panel 0..23
    const int wuni = __builtin_amdgcn_readfirstlane(wave);

    f4v acc[4][4];
    #pragma unroll
    for (int i = 0; i < 4; i++)
        #pragma unroll
        for (int j = 0; j < 4; j++)
            acc[i][j] = f4v{0.f, 0.f, 0.f, 0.f};

    for (int k0 = 0; k0 < 1024; k0 += 64) {
        __syncthreads();
        #pragma unroll
        for (int i = 0; i < 4; i++) {
            int ci = i * 256 + t;
            int row = ci >> 3;
            int csrc = (ci & 7) ^ (row & 7);
            gload_lds16(A + (size_t)(m0 + row) * 1024 + k0 + csrc * 8,
                        (char*)lds_a + i * 4096 + wuni * 1024);
            gload_lds16(Bm + (size_t)(n0 + row) * 1024 + k0 + csrc * 8,
                        (char*)lds_b + i * 4096 + wuni * 1024);
        }
        __syncthreads();

        #pragma unroll
        for (int kk = 0; kk < 2; kk++) {
            s8v afr[4], bfr[4];
            #pragma unroll
            for (int mb = 0; mb < 4; mb++) {
                int r = wm * 64 + mb * 16 + l16;
                int ch = (kk * 4 + quad) ^ (l16 & 7);
                afr[mb] = *reinterpret_cast<const s8v*>(&lds_a[r * 64 + ch * 8]);
            }
            #pragma unroll
            for (int nb = 0; nb < 4; nb++) {
                int r = wn * 64 + nb * 16 + l16;
                int ch = (kk * 4 + quad) ^ (l16 & 7);
                bfr[nb] = *reinterpret_cast<const s8v*>(&lds_b[r * 64 + ch * 8]);
            }
            #pragma unroll
            for (int mb = 0; mb < 4; mb++)
                #pragma unroll
                for (int nb = 0; nb < 4; nb++)
                    acc[mb][nb] = mfma_bf16(bfr[nb], afr[mb], acc[mb][nb]);
        }
    }

    // ---- fused epilogue; n0 (wave-uniform) selects region ----
    const int region = n0 >> 10;             // 0=Q, 1=K, 2=V
    if (region < 2) {
        const bool f32 = detect_f32((const unsigned int*)cos_t);
        #pragma unroll
        for (int mb = 0; mb < 4; mb++) {
            const int m = m0 + wm * 64 + mb * 16 + l16;
            const int b = m >> 11, s = m & 2047;
            #pragma unroll
            for (int nb = 0; nb < 4; nb++) {
                const int n = n0 + wn * 64 + nb * 16 + quad * 4;
                const int d = n & 63;                 // = nb*16 + quad*4
                const int h = (n >> 6) & 15;
                const float sgn = (nb < 2) ? -1.f : 1.f;
                f4v v  = acc[mb][nb];
                f4v vp = acc[mb][nb ^ 2];             // partner (d+32)&63, same lane
                float cs[4], sn[4];
                if (f32) {
                    float4 c4 = *reinterpret_cast<const float4*>(
                        (const float*)cos_t + s * 64 + d);
                    float4 s4 = *reinterpret_cast<const float4*>(
                        (const float*)sin_t + s * 64 + d);
                    cs[0] = c4.x; cs[1] = c4.y; cs[2] = c4.z; cs[3] = c4.w;
                    sn[0] = s4.x; sn[1] = s4.y; sn[2] = s4.z; sn[3] = s4.w;
                } else {
                    const bf16* cp = (const bf16*)cos_t + s * 64 + d;
                    const bf16* sp = (const bf16*)sin_t + s * 64 + d;
                    #pragma unroll
                    for (int r = 0; r < 4; r++) {
                        cs[r] = __bfloat162float(cp[r]);
                        sn[r] = __bfloat162float(sp[r]);
                    }
                }
                float y[4];
                #pragma unroll
                for (int r = 0; r < 4; r++)
                    y[r] = v[r] * cs[r] + sgn * vp[r] * sn[r];
                if (region == 0) {
                    // Q: pre-scale 1/8 * log2(e) for exp2-based softmax
                    size_t o = ((size_t)(b * H_ + h) * S_ + s) * 64 + d;
                    *reinterpret_cast<int2*>(&Qh[o]) =
                        pack4bf(y[0] * 0.180336880f, y[1] * 0.180336880f,
                                y[2] * 0.180336880f, y[3] * 0.180336880f);
                } else {
                    size_t kt = ((size_t)(b * H_ + h) * 32 + (s >> 6)) * 4096;
                    int dp = ((((d >> 3) ^ (s & 7)) << 3) | (d & 7));
                    *reinterpret_cast<int2*>(&Kt[kt + (s & 63) * 64 + dp]) =
                        pack4bf(y[0], y[1], y[2], y[3]);
                }
            }
        }
    } else {
        // V: 128x128 LDS transpose. lds_a = rows 0..63, lds_b = rows 64..127
        // of the [key][d] tile (row stride 128, chunk-XOR swizzled by row&7).
        __syncthreads();                     // all MFMA-phase reads complete
        bf16* half_w = (wm == 0) ? lds_a : lds_b;   // wm picks row half
        #pragma unroll
        for (int mb = 0; mb < 4; mb++) {
            const int slr = mb * 16 + l16;           // row within half (0..63)
            #pragma unroll
            for (int nb = 0; nb < 4; nb++) {
                const int nl = wn * 64 + nb * 16 + quad * 4;  // local d 0..127
                f4v v = acc[mb][nb];
                // slr&7 == (wm*64+slr)&7: swizzle consistent across halves
                int off = (((nl >> 3) ^ (slr & 7)) << 3) | (nl & 7);
                *reinterpret_cast<int2*>(&half_w[slr * 128 + off]) =
                    pack4bf(v[0], v[1], v[2], v[3]);
            }
        }
        __syncthreads();
        const int b  = m0 >> 11;
        const int h0 = (n0 - 2048) >> 6;
        const int r0 = t & 7;                        // per-lane read rotation
        #pragma unroll
        for (int i = 0; i < 8; i++) {
            int id  = i * 256 + t;                   // 0..2047 int4 outputs
            int kc  = id & 7;                        // key 8-chunk
            int d   = (id >> 3) & 63;
            int sbl = (id >> 9) & 1;                 // which 64-key subtile
            int hh  = id >> 10;                      // which head half
            int cb  = (hh << 3) | (d >> 3);          // base LDS chunk of nl
            const short* half_r = reinterpret_cast<const short*>(
                sbl ? lds_b : lds_a);
            union { short s_[8]; int4 v4; } u;
            #pragma unroll
            for (int j = 0; j < 8; j++) {
                int e   = (j + r0) & 7;
                int slr = kc * 8 + e;                // row within half; slr&7==e
                u.s_[e] = half_r[slr * 128 + (((cb ^ e) << 3) | (d & 7))];
            }
            size_t tb = ((size_t)(b * H_ + h0 + hh) * 32 +
                         ((m0 & 2047) >> 6) + sbl) * 4096;
            *reinterpret_cast<int4*>(&Vt[tb + d * 64 + ((kc ^ (d & 7)) << 3)]) = u.v4;
        }
    }
}

// ---------------------------------------------------------------------------
// Flash attention v8: CAUSAL PAIRING (512 blocks, uniform 33 iters, perfect
// 2-blocks/CU makespan -- R8 proved single-qb splitting loses to this) +
// DEPTH-2 COUNTED-vmcnt PIPELINE (T3/T4): V[kt+1]/K[kt+2] staged one full
// iter ahead into TRIPLE buffers; barrier = s_waitcnt vmcnt(N)+s_barrier
// where N = loads issued THIS iter (4/2/0, block-uniform), so the retired
// loads flew for a whole iteration of compute instead of ~300 cycles.
// Ledger (steady): start-of-iter outstanding = {V[kt],K[kt+1]} (4); issue
// {V[kt+1],K[kt+2]} (->8); vmcnt(4) retires exactly the old 4. Buffer reuse
// distance 3 > prefetch depth 2; cross-pass v_buf race guarded by a full
// __syncthreads at pass start. LDS 57 KB -> still 2 blocks/CU.
// s_setprio(1) wraps both MFMA clusters (T5).
// ---------------------------------------------------------------------------
__global__ __launch_bounds__(256)
void attn_fused(const bf16* __restrict__ Qh, const bf16* __restrict__ Kt,
                const bf16* __restrict__ Vt, const int* __restrict__ lengths,
                bf16* __restrict__ out) {
    __shared__ bf16 k_buf[3 * 4096];   // K tiles  [row(key)][chunk^(key&7)]
    __shared__ bf16 v_buf[3 * 4096];   // Vt tiles [row(d)][keychunk^(d&7)]
    __shared__ bf16 lds_p[4 * 16 * 72];// per-wave P tile [qrow][key]

    const int t = threadIdx.x, wave = t >> 6, lane = t & 63;
    const int quad = lane >> 4, l16 = lane & 15;
    // XCD-clustered decode: 512 blocks, 64 slots/XCD = 4 bh x 16 pairs
    const int bid = blockIdx.x;
    const int slot = bid >> 3;                    // 0..63
    const int bh = (bid & 7) * 4 + (slot >> 4);   // all of a bh on one XCD
    const int p = slot & 15;                      // pair index
    const int b = bh >> 4, h = bh & 15;

    const size_t hb = (size_t)bh * S_ * 64;          // Qh base
    const bf16* Ktp = Kt + (size_t)bh * 32 * 4096;   // tile array base
    const bf16* Vtp = Vt + (size_t)bh * 32 * 4096;
    const int wuni = __builtin_amdgcn_readfirstlane(wave);
    int len_raw = lengths[b];
    const int len_b = len_raw < 1 ? 1 : (len_raw > S_ ? S_ : len_raw);
    const int nkt_len = (len_b + 63) >> 6;

    #pragma unroll
    for (int pass = 0; pass < 2; pass++) {
        const int qb = pass ? (31 - p) : p;
        const int qrow_g = qb * 64 + wave * 16 + l16;   // this lane's q-row
        const int kmax = (qrow_g < len_b - 1) ? qrow_g : (len_b - 1);

        s8v qf[2];
        {
            const bf16* qptr = Qh + hb + (size_t)qrow_g * 64 + quad * 8;
            qf[0] = *reinterpret_cast<const s8v*>(qptr);
            qf[1] = *reinterpret_cast<const s8v*>(qptr + 32);
        }

        f4v o_acc[4];
        #pragma unroll
        for (int a = 0; a < 4; a++) o_acc[a] = f4v{0.f, 0.f, 0.f, 0.f};
        float l_sum = 0.f;

        const int nkt = (qb + 1) < nkt_len ? (qb + 1) : nkt_len;

        f4v s_prev[4];
        auto process_tile = [&](int pt, const bf16* vb) {
            const int pbase = pt * 64;
            const bool tail = (pt == qb) || (pbase + 64 > len_b);  // uniform
            #pragma unroll
            for (int a = 0; a < 4; a++) {
                float e0[4];
                #pragma unroll
                for (int r = 0; r < 4; r++) {
                    float e = __builtin_amdgcn_exp2f(s_prev[a][r]);
                    if (tail) {
                        int key = pbase + a * 16 + quad * 4 + r;
                        e = (key <= kmax) ? e : 0.f;
                    }
                    e0[r] = e;
                    l_sum += e;
                }
                *reinterpret_cast<int2*>(
                    &lds_p[(wave * 16 + l16) * 72 + a * 16 + quad * 4]) =
                    pack4bf(e0[0], e0[1], e0[2], e0[3]);
            }
            // wave-local: P writes -> P reads (lds_p region is per-wave)
            asm volatile("s_waitcnt lgkmcnt(0)" ::: "memory");
            __builtin_amdgcn_s_setprio(1);
            #pragma unroll
            for (int kk = 0; kk < 2; kk++) {
                s8v pf = *reinterpret_cast<const s8v*>(
                    &lds_p[(wave * 16 + l16) * 72 + kk * 32 + quad * 8]);
                #pragma unroll
                for (int a = 0; a < 4; a++) {
                    int ch = (kk * 4 + quad) ^ (l16 & 7);
                    s8v vf = *reinterpret_cast<const s8v*>(
                        &vb[(a * 16 + l16) * 64 + ch * 8]);
                    o_acc[a] = mfma_bf16(vf, pf, o_acc[a]);
                }
            }
            __builtin_amdgcn_s_setprio(0);
        };

        // pass guard: prior pass's v_buf/lds_p reads done before restaging
        // (full drain once per pass; also resets vmcnt ledger to 0)
        __syncthreads();

        // prologue: stage K[0], V[0], and K[1] (if any). Ledger after issue:
        // {K0(2), V0(2), [K1(2)]}. Need K0 retired -> vmcnt(outstanding-2).
        #pragma unroll
        for (int i = 0; i < 2; i++)
            gload_lds16(Ktp + (i * 256 + t) * 8,
                        (char*)k_buf + i * 4096 + wuni * 1024);
        #pragma unroll
        for (int i = 0; i < 2; i++)
            gload_lds16(Vtp + (i * 256 + t) * 8,
                        (char*)v_buf + i * 4096 + wuni * 1024);
        if (nkt > 1) {
            const bf16* kst = Ktp + 4096;
            #pragma unroll
            for (int i = 0; i < 2; i++)
                gload_lds16(kst + (i * 256 + t) * 8,
                            (char*)k_buf + 8192 + i * 4096 + wuni * 1024);
            asm volatile("s_waitcnt vmcnt(4)\n\ts_barrier" ::: "memory");
        } else {
            asm volatile("s_waitcnt vmcnt(2)\n\ts_barrier" ::: "memory");
        }

        for (int kt = 0; kt < nkt; kt++) {
            // prefetch one iter ahead: V[kt+1] -> vbuf[(kt+1)%3]
            if (kt + 1 < nkt) {
                const bf16* vst = Vtp + (size_t)(kt + 1) * 4096;
                const int vb3 = (kt + 1) % 3;
                #pragma unroll
                for (int i = 0; i < 2; i++)
                    gload_lds16(vst + (i * 256 + t) * 8,
                                (char*)v_buf + vb3 * 8192 + i * 4096 + wuni * 1024);
            }
            // prefetch two iters ahead: K[kt+2] -> kbuf[(kt+2)%3]
            if (kt + 2 < nkt) {
                const bf16* kst = Ktp + (size_t)(kt + 2) * 4096;
                const int kb3 = (kt + 2) % 3;
                #pragma unroll
                for (int i = 0; i < 2; i++)
                    gload_lds16(kst + (i * 256 + t) * 8,
                                (char*)k_buf + kb3 * 8192 + i * 4096 + wuni * 1024);
            }

            // S^T[kt] = K Q^T : lane holds (key = a*16+quad*4+r, qrow = l16)
            const bf16* kb = k_buf + (kt % 3) * 4096;
            f4v s_acc[4];
            #pragma unroll
            for (int a = 0; a < 4; a++) s_acc[a] = f4v{0.f, 0.f, 0.f, 0.f};
            __builtin_amdgcn_s_setprio(1);
            #pragma unroll
            for (int kk = 0; kk < 2; kk++) {
                #pragma unroll
                for (int a = 0; a < 4; a++) {
                    int ch = (kk * 4 + quad) ^ (l16 & 7);
                    s8v kf = *reinterpret_cast<const s8v*>(
                        &kb[(a * 16 + l16) * 64 + ch * 8]);
                    s_acc[a] = mfma_bf16(kf, qf[kk], s_acc[a]);
                }
            }
            __builtin_amdgcn_s_setprio(0);

            // overlap: previous tile's exp/pack/PV under this tile's S-MFMA
            if (kt > 0) process_tile(kt - 1, v_buf + ((kt - 1) % 3) * 4096);

            #pragma unroll
            for (int a = 0; a < 4; a++) s_prev[a] = s_acc[a];

            // counted barrier: retire everything EXCEPT the loads issued this
            // iter (they fly through the next iter's compute). Block-uniform.
            if (kt + 2 < nkt) {
                asm volatile("s_waitcnt vmcnt(4)\n\ts_barrier" ::: "memory");
            } else if (kt + 1 < nkt) {
                asm volatile("s_waitcnt vmcnt(2)\n\ts_barrier" ::: "memory");
            } else {
                asm volatile("s_waitcnt vmcnt(0)\n\ts_barrier" ::: "memory");
            }
        }
        // drain: last tile (V[nkt-1] retired by the final vmcnt(0))
        process_tile(nkt - 1, v_buf + ((nkt - 1) % 3) * 4096);

        // reduce l across the 4 quads sharing this q-row, then b64 epilogue
        l_sum += __shfl_xor(l_sum, 16);
        l_sum += __shfl_xor(l_sum, 32);
        float inv_l = 1.f / l_sum;
        size_t orow = ((size_t)(b * S_ + qrow_g)) * TD_ + h * 64;
        #pragma unroll
        for (int a = 0; a < 4; a++) {
            *reinterpret_cast<int2*>(&out[orow + a * 16 + quad * 4]) =
                pack4bf(o_acc[a][0] * inv_l, o_acc[a][1] * inv_l,
                        o_acc[a][2] * inv_l, o_acc[a][3] * inv_l);
        }
    }
}

// ---------------------------------------------------------------------------
extern "C" void kernel_launch(void* const* d_in, const int* in_sizes, int n_in,
                              void* d_out, int out_size, void* d_ws, size_t ws_size,
                              hipStream_t stream) {
    const void* query = d_in[0];   // [B,S,DM]  fp32 (auto-detected, bf16-safe)
    const void* W_in  = d_in[1];   // [3TD,DM]
    const void* W_out = d_in[2];   // [DM,TD]
    const void* sin_q = d_in[3];   // [S,HD]
    const void* cos_q = d_in[4];   // [S,HD]   dtype probe
    const void* mask  = d_in[5];   // [B,S] bool, storage auto-detected
    const unsigned int* cosw = (const unsigned int*)cos_q;

    const size_t nQ  = NQ_;   // 4194304
    const size_t nWi = NWI_;  // 3145728
    const size_t nWo = NWO_;  // 1048576

    // Workspace layout (no aliasing hazards: gemm_qkv reads qbf/wibf and
    // writes Qh/Kt/Vt; attn reads Qh/Kt/Vt and writes attn; all disjoint).
    bf16* base = (bf16*)d_ws;
    bf16* attn = base;                               // [4096,1024] attn out
    bf16* Vt   = base + (size_t)4096 * 1024;         // tiled+swizzled V
    bf16* Qh   = base + (size_t)2 * 4096 * 1024;     // [B,H,S,64] linear
    bf16* Kt   = Qh + nQ;                            // tiled+swizzled K
    bf16* qbf  = Kt + nQ;                            // query bf16
    bf16* wibf = qbf + nQ;
    bf16* wobf = wibf + nWi;
    int* lengths = (int*)(wobf + nWo);

    prep_all<<<NCVT_BLOCKS + B_, 256, 0, stream>>>(
        query, W_in, W_out, qbf, mask, lengths, cosw);

    gemm_qkv<<<768, 256, 0, stream>>>(qbf, wibf, Qh, Kt, Vt, sin_q, cos_q);

    attn_fused<<<512, 256, 0, stream>>>(Qh, Kt, Vt, lengths, attn);

    gemm_out<<<512, 256, 0, stream>>>(attn, wobf, d_out, 4096, 1024, 1024, 1, cosw);
}

// Round 10
// 176.975 us; speedup vs baseline: 1.0983x; 1.0164x over previous
//
#include <hip/hip_runtime.h>
#include <hip/hip_bf16.h>

// Problem constants
#define B_ 2
#define S_ 2048
#define DM_ 1024
#define TD_ 1024
#define H_ 16
#define HD_ 64

using bf16 = __hip_bfloat16;
typedef __attribute__((ext_vector_type(8))) short s8v;   // 8 bf16 = one MFMA A/B frag
typedef __attribute__((ext_vector_type(4))) float f4v;   // MFMA C/D frag

__device__ __forceinline__ f4v mfma_bf16(s8v a, s8v b, f4v c) {
    return __builtin_amdgcn_mfma_f32_16x16x32_bf16(a, b, c, 0, 0, 0);
}

// HW packed fp32x2 -> bf16x2 (RNE), single VOP3 instr on CDNA3/4
__device__ __forceinline__ unsigned cvt_pk_bf16(float a, float b) {
    unsigned r;
    asm("v_cvt_pk_bf16_f32 %0, %1, %2" : "=v"(r) : "v"(a), "v"(b));
    return r;
}
__device__ __forceinline__ int2 pack4bf(float a, float b, float c, float d) {
    int2 r;
    r.x = (int)cvt_pk_bf16(a, b);
    r.y = (int)cvt_pk_bf16(c, d);
    return r;
}

// cos_q[0] == 1.0 exactly: fp32 word = 0x3F800000 (low16==0); bf16 pair != 0 low16.
__device__ __forceinline__ bool detect_f32(const unsigned int* __restrict__ cosw) {
    return (cosw[0] & 0xFFFFu) == 0u;
}

// async global -> LDS, 16 B per lane (HW: dst = wave-uniform base + lane*16)
__device__ __forceinline__ void gload_lds16(const bf16* g, void* l) {
    __builtin_amdgcn_global_load_lds(
        (const __attribute__((address_space(1))) unsigned int*)(const void*)g,
        (__attribute__((address_space(3))) unsigned int*)l,
        16, 0, 0);
}

#define NQ_  (B_ * S_ * DM_)
#define NWI_ (3 * TD_ * DM_)
#define NWO_ (DM_ * TD_)
#define NCVT_BLOCKS ((NQ_ + NWI_ + NWO_) / 2048)   // 4096

// ---------------------------------------------------------------------------
// Fused prep: blocks [0,4096) convert (query|W_in|W_out) -> bf16;
// blocks 4096..4097 compute lengths[b] from the mask (4-way storage detect).
// ---------------------------------------------------------------------------
__global__ __launch_bounds__(256)
void prep_all(const void* __restrict__ q, const void* __restrict__ wi,
              const void* __restrict__ wo, bf16* __restrict__ dst,
              const void* __restrict__ mask, int* __restrict__ lengths,
              const unsigned int* __restrict__ cosw) {
    const int bid = blockIdx.x;
    if (bid < NCVT_BLOCKS) {
        const bool f32 = detect_f32(cosw);
        int i = (bid * 256 + threadIdx.x) * 8;
        const void* src; int off;
        if (i < NQ_)              { src = q;  off = i; }
        else if (i < NQ_ + NWI_)  { src = wi; off = i - NQ_; }
        else                      { src = wo; off = i - NQ_ - NWI_; }
        if (f32) {
            const float* p = (const float*)src + off;
            float4 x = *reinterpret_cast<const float4*>(p);
            float4 y = *reinterpret_cast<const float4*>(p + 4);
            union { unsigned u[4]; int4 v; } t;
            t.u[0] = cvt_pk_bf16(x.x, x.y);
            t.u[1] = cvt_pk_bf16(x.z, x.w);
            t.u[2] = cvt_pk_bf16(y.x, y.y);
            t.u[3] = cvt_pk_bf16(y.z, y.w);
            *reinterpret_cast<int4*>(dst + i) = t.v;
        } else {
            *reinterpret_cast<int4*>(dst + i) =
                *reinterpret_cast<const int4*>((const bf16*)src + off);
        }
        return;
    }
    // lengths path
    int b = bid - NCVT_BLOCKS;
    unsigned int w0 = ((const unsigned int*)mask)[0];
    int enc;                 // 0=i32, 1=u8, 2=bf16, 3=f32
    if (w0 == 1u) enc = 0;
    else if (w0 == 0x01010101u) enc = 1;
    else if (w0 == 0x3F803F80u) enc = 2;
    else enc = 3;
    int cnt = 0;
    for (int s = threadIdx.x; s < S_; s += 256) {
        int i = b * S_ + s;
        bool v;
        if (enc == 0)      v = ((const int*)mask)[i] != 0;
        else if (enc == 1) v = ((const unsigned char*)mask)[i] != 0;
        else if (enc == 2) v = ((const unsigned short*)mask)[i] != 0;
        else               v = ((const float*)mask)[i] != 0.f;
        cnt += v ? 1 : 0;
    }
    __shared__ int red[256];
    red[threadIdx.x] = cnt;
    __syncthreads();
    for (int off = 128; off > 0; off >>= 1) {
        if (threadIdx.x < off) red[threadIdx.x] += red[threadIdx.x + off];
        __syncthreads();
    }
    if (threadIdx.x == 0) lengths[b] = red[0];
}

// ---------------------------------------------------------------------------
// Output-projection NT GEMM, BM=128 x BN=64 tile (512 blocks -> 2 blocks/CU,
// 2 waves/SIMD: one block's MFMA hides the other's staging). Proven R5 form.
// Wave covers 64m x 32n: acc[4][2] (32 AGPRs). XCD-clustered bid swizzle.
// c_dyn: 1 -> write detected dtype (fp32 if inputs fp32), 0 -> bf16.
// ---------------------------------------------------------------------------
__global__ __launch_bounds__(256, 4)
void gemm_out(const bf16* __restrict__ A, const bf16* __restrict__ Bm,
              void* __restrict__ C, int M, int N, int K,
              int c_dyn, const unsigned int* __restrict__ cosw) {
    __shared__ bf16 lds_a[128 * 64];   // 16 KB, [row][chunk^(row&7)]
    __shared__ bf16 lds_b[64 * 64];    //  8 KB

    const bool cf32 = c_dyn && detect_f32(cosw);

    const int t = threadIdx.x;
    const int wave = t >> 6, lane = t & 63;
    const int quad = lane >> 4, l16 = lane & 15;
    const int wm = wave >> 1, wn = wave & 1;
    // bijective XCD-clustered decode: 512 blocks = 8 XCD x (4 m x 16 n)
    const int bid = blockIdx.x;
    const int c = bid & 7, g = bid >> 3;            // g: 0..63
    const int m0 = (c * 4 + (g & 3)) * 128;         // m_panel 0..31
    const int n0 = (g >> 2) * 64;                   // n_idx 0..15
    const int wuni = __builtin_amdgcn_readfirstlane(wave);

    f4v acc[4][2];
    #pragma unroll
    for (int i = 0; i < 4; i++)
        #pragma unroll
        for (int j = 0; j < 2; j++)
            acc[i][j] = f4v{0.f, 0.f, 0.f, 0.f};

    for (int k0 = 0; k0 < K; k0 += 64) {
        __syncthreads();                 // prior reads done before restage
        #pragma unroll
        for (int i = 0; i < 4; i++) {
            int ci = i * 256 + t;        // A chunks 0..1023 (16B each)
            int row = ci >> 3;
            int csrc = (ci & 7) ^ (row & 7);
            gload_lds16(A + (size_t)(m0 + row) * K + k0 + csrc * 8,
                        (char*)lds_a + i * 4096 + wuni * 1024);
        }
        #pragma unroll
        for (int i = 0; i < 2; i++) {
            int ci = i * 256 + t;        // B chunks 0..511
            int row = ci >> 3;
            int csrc = (ci & 7) ^ (row & 7);
            gload_lds16(Bm + (size_t)(n0 + row) * K + k0 + csrc * 8,
                        (char*)lds_b + i * 4096 + wuni * 1024);
        }
        __syncthreads();                 // drains vmcnt -> staged data visible

        #pragma unroll
        for (int kk = 0; kk < 2; kk++) {
            s8v afr[4], bfr[2];
            #pragma unroll
            for (int mb = 0; mb < 4; mb++) {
                int r = wm * 64 + mb * 16 + l16;
                int ch = (kk * 4 + quad) ^ (l16 & 7);
                afr[mb] = *reinterpret_cast<const s8v*>(&lds_a[r * 64 + ch * 8]);
            }
            #pragma unroll
            for (int nb = 0; nb < 2; nb++) {
                int r = wn * 32 + nb * 16 + l16;
                int ch = (kk * 4 + quad) ^ (l16 & 7);
                bfr[nb] = *reinterpret_cast<const s8v*>(&lds_b[r * 64 + ch * 8]);
            }
            // swapped: D[i=n-in-16][j=m-in-16], lane j=l16, regs i=quad*4+rr
            #pragma unroll
            for (int mb = 0; mb < 4; mb++)
                #pragma unroll
                for (int nb = 0; nb < 2; nb++)
                    acc[mb][nb] = mfma_bf16(bfr[nb], afr[mb], acc[mb][nb]);
        }
    }

    // epilogue: m = m0+wm*64+mb*16+l16 (per lane), n = n0+wn*32+nb*16+quad*4+rr
    #pragma unroll
    for (int mb = 0; mb < 4; mb++) {
        int m = m0 + wm * 64 + mb * 16 + l16;
        #pragma unroll
        for (int nb = 0; nb < 2; nb++) {
            int n = n0 + wn * 32 + nb * 16 + quad * 4;
            f4v v = acc[mb][nb];
            if (cf32) {
                *reinterpret_cast<f4v*>(&((float*)C)[(size_t)m * N + n]) = v;
            } else {
                *reinterpret_cast<int2*>(&((bf16*)C)[(size_t)m * N + n]) =
                    pack4bf(v[0], v[1], v[2], v[3]);
            }
        }
    }
}

// ---------------------------------------------------------------------------
// QKV GEMM with FUSED RoPE + layout epilogue. PROVEN R5 FORM (44.2 us):
// 128x128 tile, 2-barrier K-step, lb(256,3), XCD-clustered grid 768.
// R6 (m-split) and R7 (dbuf) both regressed -- this is the local opt.
// Region by n0: [0,1024) Q, [1024,2048) K, [2048,3072) V.
// ---------------------------------------------------------------------------
__global__ __launch_bounds__(256, 3)
void gemm_qkv(const bf16* __restrict__ A, const bf16* __restrict__ Bm,
              bf16* __restrict__ Qh, bf16* __restrict__ Kt, bf16* __restrict__ Vt,
              const void* __restrict__ sin_t, const void* __restrict__ cos_t) {
    __shared__ bf16 lds_a[128 * 64];   // 16 KB, [row][chunk^(row&7)]
    __shared__ bf16 lds_b[128 * 64];

    const int t = threadIdx.x;
    const int wave = t >> 6, lane = t & 63;
    const int quad = lane >> 4, l16 = lane & 15;
    const int wm = wave >> 1, wn = wave & 1;
    // bijective XCD-clustered decode: 768 blocks = 8 XCD x (4 m x 24 n)
    const int bid = blockIdx.x;
    const int c = bid & 7, g = bid >> 3;            // g: 0..95
    const int m0 = (c * 4 + (g & 3)) * 128;         // m_panel 0..31
    const int n0 = (g >> 2) * 128;                  // n_panel 0..23
    const int wuni = __builtin_amdgcn_readfirstlane(wave);

    f4v acc[4][4];
    #pragma unroll
    for (int i = 0; i < 4; i++)
        #pragma unroll
        for (int j = 0; j < 4; j++)
            acc[i][j] = f4v{0.f, 0.f, 0.f, 0.f};

    for (int k0 = 0; k0 < 1024; k0 += 64) {
        __syncthreads();
        #pragma unroll
        for (int i = 0; i < 4; i++) {
            int ci = i * 256 + t;
            int row = ci >> 3;
            int csrc = (ci & 7) ^ (row & 7);
            gload_lds16(A + (size_t)(m0 + row) * 1024 + k0 + csrc * 8,
                        (char*)lds_a + i * 4096 + wuni * 1024);
            gload_lds16(Bm + (size_t)(n0 + row) * 1024 + k0 + csrc * 8,
                        (char*)lds_b + i * 4096 + wuni * 1024);
        }
        __syncthreads();

        #pragma unroll
        for (int kk = 0; kk < 2; kk++) {
            s8v afr[4], bfr[4];
            #pragma unroll
            for (int mb = 0; mb < 4; mb++) {
                int r = wm * 64 + mb * 16 + l16;
                int ch = (kk * 4 + quad) ^ (l16 & 7);
                afr[mb] = *reinterpret_cast<const s8v*>(&lds_a[r * 64 + ch * 8]);
            }
            #pragma unroll
            for (int nb = 0; nb < 4; nb++) {
                int r = wn * 64 + nb * 16 + l16;
                int ch = (kk * 4 + quad) ^ (l16 & 7);
                bfr[nb] = *reinterpret_cast<const s8v*>(&lds_b[r * 64 + ch * 8]);
            }
            #pragma unroll
            for (int mb = 0; mb < 4; mb++)
                #pragma unroll
                for (int nb = 0; nb < 4; nb++)
                    acc[mb][nb] = mfma_bf16(bfr[nb], afr[mb], acc[mb][nb]);
        }
    }

    // ---- fused epilogue; n0 (wave-uniform) selects region ----
    const int region = n0 >> 10;             // 0=Q, 1=K, 2=V
    if (region < 2) {
        const bool f32 = detect_f32((const unsigned int*)cos_t);
        #pragma unroll
        for (int mb = 0; mb < 4; mb++) {
            const int m = m0 + wm * 64 + mb * 16 + l16;
            const int b = m >> 11, s = m & 2047;
            #pragma unroll
            for (int nb = 0; nb < 4; nb++) {
                const int n = n0 + wn * 64 + nb * 16 + quad * 4;
                const int d = n & 63;                 // = nb*16 + quad*4
                const int h = (n >> 6) & 15;
                const float sgn = (nb < 2) ? -1.f : 1.f;
                f4v v  = acc[mb][nb];
                f4v vp = acc[mb][nb ^ 2];             // partner (d+32)&63, same lane
                float cs[4], sn[4];
                if (f32) {
                    float4 c4 = *reinterpret_cast<const float4*>(
                        (const float*)cos_t + s * 64 + d);
                    float4 s4 = *reinterpret_cast<const float4*>(
                        (const float*)sin_t + s * 64 + d);
                    cs[0] = c4.x; cs[1] = c4.y; cs[2] = c4.z; cs[3] = c4.w;
                    sn[0] = s4.x; sn[1] = s4.y; sn[2] = s4.z; sn[3] = s4.w;
                } else {
                    const bf16* cp = (const bf16*)cos_t + s * 64 + d;
                    const bf16* sp = (const bf16*)sin_t + s * 64 + d;
                    #pragma unroll
                    for (int r = 0; r < 4; r++) {
                        cs[r] = __bfloat162float(cp[r]);
                        sn[r] = __bfloat162float(sp[r]);
                    }
                }
                float y[4];
                #pragma unroll
                for (int r = 0; r < 4; r++)
                    y[r] = v[r] * cs[r] + sgn * vp[r] * sn[r];
                if (region == 0) {
                    // Q: pre-scale 1/8 * log2(e) for exp2-based softmax
                    size_t o = ((size_t)(b * H_ + h) * S_ + s) * 64 + d;
                    *reinterpret_cast<int2*>(&Qh[o]) =
                        pack4bf(y[0] * 0.180336880f, y[1] * 0.180336880f,
                                y[2] * 0.180336880f, y[3] * 0.180336880f);
                } else {
                    size_t kt = ((size_t)(b * H_ + h) * 32 + (s >> 6)) * 4096;
                    int dp = ((((d >> 3) ^ (s & 7)) << 3) | (d & 7));
                    *reinterpret_cast<int2*>(&Kt[kt + (s & 63) * 64 + dp]) =
                        pack4bf(y[0], y[1], y[2], y[3]);
                }
            }
        }
    } else {
        // V: 128x128 LDS transpose. lds_a = rows 0..63, lds_b = rows 64..127
        // of the [key][d] tile (row stride 128, chunk-XOR swizzled by row&7).
        __syncthreads();                     // all MFMA-phase reads complete
        bf16* half_w = (wm == 0) ? lds_a : lds_b;   // wm picks row half
        #pragma unroll
        for (int mb = 0; mb < 4; mb++) {
            const int slr = mb * 16 + l16;           // row within half (0..63)
            #pragma unroll
            for (int nb = 0; nb < 4; nb++) {
                const int nl = wn * 64 + nb * 16 + quad * 4;  // local d 0..127
                f4v v = acc[mb][nb];
                // slr&7 == (wm*64+slr)&7: swizzle consistent across halves
                int off = (((nl >> 3) ^ (slr & 7)) << 3) | (nl & 7);
                *reinterpret_cast<int2*>(&half_w[slr * 128 + off]) =
                    pack4bf(v[0], v[1], v[2], v[3]);
            }
        }
        __syncthreads();
        const int b  = m0 >> 11;
        const int h0 = (n0 - 2048) >> 6;
        const int r0 = t & 7;                        // per-lane read rotation
        #pragma unroll
        for (int i = 0; i < 8; i++) {
            int id  = i * 256 + t;                   // 0..2047 int4 outputs
            int kc  = id & 7;                        // key 8-chunk
            int d   = (id >> 3) & 63;
            int sbl = (id >> 9) & 1;                 // which 64-key subtile
            int hh  = id >> 10;                      // which head half
            int cb  = (hh << 3) | (d >> 3);          // base LDS chunk of nl
            const short* half_r = reinterpret_cast<const short*>(
                sbl ? lds_b : lds_a);
            union { short s_[8]; int4 v4; } u;
            #pragma unroll
            for (int j = 0; j < 8; j++) {
                int e   = (j + r0) & 7;
                int slr = kc * 8 + e;                // row within half; slr&7==e
                u.s_[e] = half_r[slr * 128 + (((cb ^ e) << 3) | (d & 7))];
            }
            size_t tb = ((size_t)(b * H_ + h0 + hh) * 32 +
                         ((m0 & 2047) >> 6) + sbl) * 4096;
            *reinterpret_cast<int4*>(&Vt[tb + d * 64 + ((kc ^ (d & 7)) << 3)]) = u.v4;
        }
    }
}

// ---------------------------------------------------------------------------
// Flash attention v9: R5-proven skeleton (CAUSAL PAIRING 512 blocks, uniform
// 33 iters, perfect 2-blocks/CU makespan; 2-buffer staging; plain
// __syncthreads; setprio around MFMA clusters) + ONES-MFMA ROW-SUM:
// l_sum is no longer 16 serial VALU fadds inside the exp chain -- the packed
// P fragment is fed through one extra MFMA per kk with an all-ones A-operand,
// yielding the full 64-key row sum per q-row on the (14%-idle) MFMA pipe.
// Also removes the end-of-pass shfl_xor quad-reduction (MFMA reduces across
// quads already), and makes numerator/denominator use identical bf16 P.
// R7/R9 counted-vmcnt pipelines both regressed: attn is VALU-chain-bound,
// not load-latency-bound (R9: VALUBusy 34%, MfmaUtil 14%).
// ---------------------------------------------------------------------------
__global__ __launch_bounds__(256)
void attn_fused(const bf16* __restrict__ Qh, const bf16* __restrict__ Kt,
                const bf16* __restrict__ Vt, const int* __restrict__ lengths,
                bf16* __restrict__ out) {
    __shared__ bf16 k_buf[2 * 4096];   // K tiles  [row(key)][chunk^(key&7)]
    __shared__ bf16 v_buf[2 * 4096];   // Vt tiles [row(d)][keychunk^(d&7)]
    __shared__ bf16 lds_p[4 * 16 * 72];// per-wave P tile [qrow][key]

    const int t = threadIdx.x, wave = t >> 6, lane = t & 63;
    const int quad = lane >> 4, l16 = lane & 15;
    // XCD-clustered decode: 512 blocks, 64 slots/XCD = 4 bh x 16 pairs
    const int bid = blockIdx.x;
    const int slot = bid >> 3;                    // 0..63
    const int bh = (bid & 7) * 4 + (slot >> 4);   // all of a bh on one XCD
    const int p = slot & 15;                      // pair index
    const int b = bh >> 4, h = bh & 15;

    const size_t hb = (size_t)bh * S_ * 64;          // Qh base
    const bf16* Ktp = Kt + (size_t)bh * 32 * 4096;   // tile array base
    const bf16* Vtp = Vt + (size_t)bh * 32 * 4096;
    const int wuni = __builtin_amdgcn_readfirstlane(wave);
    int len_raw = lengths[b];
    const int len_b = len_raw < 1 ? 1 : (len_raw > S_ ? S_ : len_raw);
    const int nkt_len = (len_b + 63) >> 6;

    // all-ones bf16 A-operand for the row-sum MFMA
    s8v ones;
    #pragma unroll
    for (int i = 0; i < 8; i++) ones[i] = (short)0x3F80;

    #pragma unroll
    for (int pass = 0; pass < 2; pass++) {
        const int qb = pass ? (31 - p) : p;
        const int qrow_g = qb * 64 + wave * 16 + l16;   // this lane's q-row
        const int kmax = (qrow_g < len_b - 1) ? qrow_g : (len_b - 1);

        s8v qf[2];
        {
            const bf16* qptr = Qh + hb + (size_t)qrow_g * 64 + quad * 8;
            qf[0] = *reinterpret_cast<const s8v*>(qptr);
            qf[1] = *reinterpret_cast<const s8v*>(qptr + 32);
        }

        f4v o_acc[4];
        #pragma unroll
        for (int a = 0; a < 4; a++) o_acc[a] = f4v{0.f, 0.f, 0.f, 0.f};
        f4v l_acc = f4v{0.f, 0.f, 0.f, 0.f};   // row-sum via ones-MFMA

        const int nkt = (qb + 1) < nkt_len ? (qb + 1) : nkt_len;

        f4v s_prev[4];
        auto process_tile = [&](int pt, const bf16* vb) {
            const int pbase = pt * 64;
            const bool tail = (pt == qb) || (pbase + 64 > len_b);  // uniform
            #pragma unroll
            for (int a = 0; a < 4; a++) {
                float e0[4];
                #pragma unroll
                for (int r = 0; r < 4; r++) {
                    float e = __builtin_amdgcn_exp2f(s_prev[a][r]);
                    if (tail) {
                        int key = pbase + a * 16 + quad * 4 + r;
                        e = (key <= kmax) ? e : 0.f;
                    }
                    e0[r] = e;
                }
                *reinterpret_cast<int2*>(
                    &lds_p[(wave * 16 + l16) * 72 + a * 16 + quad * 4]) =
                    pack4bf(e0[0], e0[1], e0[2], e0[3]);
            }
            // wave-local: P writes -> P reads (lds_p region is per-wave)
            asm volatile("s_waitcnt lgkmcnt(0)" ::: "memory");
            __builtin_amdgcn_s_setprio(1);
            #pragma unroll
            for (int kk = 0; kk < 2; kk++) {
                s8v pf = *reinterpret_cast<const s8v*>(
                    &lds_p[(wave * 16 + l16) * 72 + kk * 32 + quad * 8]);
                l_acc = mfma_bf16(ones, pf, l_acc);   // row sum on MFMA pipe
                #pragma unroll
                for (int a = 0; a < 4; a++) {
                    int ch = (kk * 4 + quad) ^ (l16 & 7);
                    s8v vf = *reinterpret_cast<const s8v*>(
                        &vb[(a * 16 + l16) * 64 + ch * 8]);
                    o_acc[a] = mfma_bf16(vf, pf, o_acc[a]);
                }
            }
            __builtin_amdgcn_s_setprio(0);
        };

        // prologue: stage K[0] (pass-0 drain reads only v_buf/lds_p; no race)
        #pragma unroll
        for (int i = 0; i < 2; i++) {
            int ci = i * 256 + t;
            gload_lds16(Ktp + ci * 8, (char*)k_buf + i * 4096 + wuni * 1024);
        }
        __syncthreads();   // K[0] resident (drains vmcnt)

        for (int kt = 0; kt < nkt; kt++) {
            const int cur = kt & 1;
            // stage V[kt] -> vbuf[cur] (one tile behind K)
            {
                const bf16* vst = Vtp + (size_t)kt * 4096;
                #pragma unroll
                for (int i = 0; i < 2; i++) {
                    int ci = i * 256 + t;
                    gload_lds16(vst + ci * 8,
                                (char*)v_buf + cur * 8192 + i * 4096 + wuni * 1024);
                }
            }
            // stage K[kt+1] -> kbuf[cur^1]
            if (kt + 1 < nkt) {
                const bf16* kst = Ktp + (size_t)(kt + 1) * 4096;
                #pragma unroll
                for (int i = 0; i < 2; i++) {
                    int ci = i * 256 + t;
                    gload_lds16(kst + ci * 8,
                                (char*)k_buf + (cur ^ 1) * 8192 + i * 4096 + wuni * 1024);
                }
            }

            // S^T[kt] = K Q^T : lane holds (key = a*16+quad*4+r, qrow = l16)
            const bf16* kb = k_buf + cur * 4096;
            f4v s_acc[4];
            #pragma unroll
            for (int a = 0; a < 4; a++) s_acc[a] = f4v{0.f, 0.f, 0.f, 0.f};
            __builtin_amdgcn_s_setprio(1);
            #pragma unroll
            for (int kk = 0; kk < 2; kk++) {
                #pragma unroll
                for (int a = 0; a < 4; a++) {
                    int ch = (kk * 4 + quad) ^ (l16 & 7);
                    s8v kf = *reinterpret_cast<const s8v*>(
                        &kb[(a * 16 + l16) * 64 + ch * 8]);
                    s_acc[a] = mfma_bf16(kf, qf[kk], s_acc[a]);
                }
            }
            __builtin_amdgcn_s_setprio(0);

            // overlap: previous tile's exp/pack/PV under this tile's S-MFMA
            if (kt > 0) process_tile(kt - 1, v_buf + ((kt - 1) & 1) * 4096);

            #pragma unroll
            for (int a = 0; a < 4; a++) s_prev[a] = s_acc[a];

            __syncthreads();   // V[kt], K[kt+1] staged; LDS reads done before reuse
        }
        // drain: last tile
        process_tile(nkt - 1, v_buf + ((nkt - 1) & 1) * 4096);

        // l_acc[0] already holds the FULL row sum for qrow (MFMA reduced
        // across all 64 keys/tile and all quads) -- no shuffle needed.
        float inv_l = 1.f / l_acc[0];
        size_t orow = ((size_t)(b * S_ + qrow_g)) * TD_ + h * 64;
        #pragma unroll
        for (int a = 0; a < 4; a++) {
            *reinterpret_cast<int2*>(&out[orow + a * 16 + quad * 4]) =
                pack4bf(o_acc[a][0] * inv_l, o_acc[a][1] * inv_l,
                        o_acc[a][2] * inv_l, o_acc[a][3] * inv_l);
        }
    }
}

// ---------------------------------------------------------------------------
extern "C" void kernel_launch(void* const* d_in, const int* in_sizes, int n_in,
                              void* d_out, int out_size, void* d_ws, size_t ws_size,
                              hipStream_t stream) {
    const void* query = d_in[0];   // [B,S,DM]  fp32 (auto-detected, bf16-safe)
    const void* W_in  = d_in[1];   // [3TD,DM]
    const void* W_out = d_in[2];   // [DM,TD]
    const void* sin_q = d_in[3];   // [S,HD]
    const void* cos_q = d_in[4];   // [S,HD]   dtype probe
    const void* mask  = d_in[5];   // [B,S] bool, storage auto-detected
    const unsigned int* cosw = (const unsigned int*)cos_q;

    const size_t nQ  = NQ_;   // 4194304
    const size_t nWi = NWI_;  // 3145728
    const size_t nWo = NWO_;  // 1048576

    // Workspace layout (no aliasing hazards: gemm_qkv reads qbf/wibf and
    // writes Qh/Kt/Vt; attn reads Qh/Kt/Vt and writes attn; all disjoint).
    bf16* base = (bf16*)d_ws;
    bf16* attn = base;                               // [4096,1024] attn out
    bf16* Vt   = base + (size_t)4096 * 1024;         // tiled+swizzled V
    bf16* Qh   = base + (size_t)2 * 4096 * 1024;     // [B,H,S,64] linear
    bf16* Kt   = Qh + nQ;                            // tiled+swizzled K
    bf16* qbf  = Kt + nQ;                            // query bf16
    bf16* wibf = qbf + nQ;
    bf16* wobf = wibf + nWi;
    int* lengths = (int*)(wobf + nWo);

    prep_all<<<NCVT_BLOCKS + B_, 256, 0, stream>>>(
        query, W_in, W_out, qbf, mask, lengths, cosw);

    gemm_qkv<<<768, 256, 0, stream>>>(qbf, wibf, Qh, Kt, Vt, sin_q, cos_q);

    attn_fused<<<512, 256, 0, stream>>>(Qh, Kt, Vt, lengths, attn);

    gemm_out<<<512, 256, 0, stream>>>(attn, wobf, d_out, 4096, 1024, 1024, 1, cosw);
}